// Round 7
// baseline (560.856 us; speedup 1.0000x reference)
//
#include <hip/hip_runtime.h>
#include <hip/hip_bf16.h>
#include <stdint.h>
#include <math.h>

#define NN   100000
#define EE   3200000
#define FIN  5
#define SHD  32
#define NH   8
#define TCH  21
#define TRH  22
#define SEQL 14

#define NPB   98
#define FPC   64
#define NC    16
#define NBUK  (NC * FPC)
#define CSZ   (NPB * FPC)
#define CAP   3712
#define CAPG1 208896
#define BCHK  4096
#define NBC1  ((EE + BCHK - 1) / BCHK)
#define PB2   ((CAPG1 + BCHK - 1) / BCHK)

typedef __hip_bfloat16 bf16;
typedef __attribute__((ext_vector_type(2))) float f32x2;

__device__ __forceinline__ float b2f(bf16 v) { return __bfloat162float(v); }
__device__ __forceinline__ float sigm(float x) { return 1.f / (1.f + __expf(-x)); }
__device__ __forceinline__ float ldw(const void* p, int i, int f) {
    return f ? ((const float*)p)[i] : __bfloat162float(((const bf16*)p)[i]);
}
__device__ __forceinline__ float relu_nan(float v) {
    return (v == v) ? ((v > 0.f) ? v : 0.f) : v;
}
__device__ __forceinline__ unsigned short f2b(float v) {
    bf16 b = __float2bfloat16(v);
    return *reinterpret_cast<unsigned short*>(&b);
}
__device__ __forceinline__ float cvf(float v) { return v; }
__device__ __forceinline__ float cvf(bf16 v) { return __bfloat162float(v); }
__device__ __forceinline__ void cp(float* dst, const void* src, int n,
                                   int t0, int stride, int f) {
    if (f) {
        const float* s = (const float*)src;
        for (int i = t0; i < n; i += stride) dst[i] = s[i];
    } else {
        const bf16* s = (const bf16*)src;
        for (int i = t0; i < n; i += stride) dst[i] = b2f(s[i]);
    }
}

// ---- dtype detect + f32 param pre-convert (identifier-named, 1 wave) ------
__global__ void PatternAwareSTGAT_94489281309_kernel(const unsigned int* xw, int* flag,
        const void* as0, const void* b0, const void* as1, const void* b1,
        const void* as2, const void* b2, float* prm) {
    int tid = threadIdx.x;   // 64
    int sane = 0;
    for (int i = 0; i < 64; i++) {
        unsigned int lo = xw[i] & 0xFFFFu;
        int e = (int)((lo >> 7) & 0xFF);
        if (e >= 110 && e <= 135) sane++;
    }
    int f = (sane >= 32) ? 0 : 1;
    if (tid == 0) flag[0] = f;
    const void* asp[3] = {as0, as1, as2};
    const void* bp[3]  = {b0, b1, b2};
    for (int l = 0; l < 3; l++)
        prm[l * 64 + tid] = (tid < 32) ? ldw(asp[l], tid, f) : ldw(bp[l], tid - 32, f);
}

// ---------------- CSR build: two-level LDS-staged counting sort --------------
__global__ __launch_bounds__(256) void k_p1(const int* __restrict__ ei,
                                            int* __restrict__ g1,
                                            int* __restrict__ rec1) {
    __shared__ int stage[BCHK];
    __shared__ int c16[NC], o16[NC], go[NC], sb[NC];
    int tid = threadIdx.x;
    if (tid < NC) c16[tid] = 0;
    __syncthreads();
    int e0 = blockIdx.x * BCHK;
    int e1 = e0 + BCHK; if (e1 > EE) e1 = EE;
    for (int e = e0 + tid; e < e1; e += 256) {
        int d = __builtin_nontemporal_load(ei + EE + e);
        atomicAdd(&c16[d / CSZ], 1);
    }
    __syncthreads();
    if (tid == 0) {
        int acc = 0;
        for (int g = 0; g < NC; g++) { sb[g] = acc; o16[g] = acc; acc += c16[g]; }
    }
    __syncthreads();
    if (tid < NC) go[tid] = (c16[tid] > 0) ? atomicAdd(&g1[tid], c16[tid]) : 0;
    __syncthreads();
    for (int e = e0 + tid; e < e1; e += 256) {
        int s = __builtin_nontemporal_load(ei + e);
        int d = __builtin_nontemporal_load(ei + EE + e);
        int g = d / CSZ;
        int p = atomicAdd(&o16[g], 1);
        stage[p] = s | ((d - g * CSZ) << 17);
    }
    __syncthreads();
    for (int g = 0; g < NC; g++) {
        int cnt = c16[g], base = go[g], sbase = sb[g];
        int* out = rec1 + (size_t)g * CAPG1;
        for (int i = tid; i < cnt; i += 256) {
            int p = base + i;
            if (p < CAPG1) out[p] = stage[sbase + i];
        }
    }
}

__global__ __launch_bounds__(256) void k_p2(const int* __restrict__ rec1,
                                            const int* __restrict__ g1,
                                            int* __restrict__ g2,
                                            int* __restrict__ rec2) {
    __shared__ int stage[BCHK];
    __shared__ int cF[FPC], oF[FPC], goF[FPC], sbF[FPC];
    int tid = threadIdx.x;
    int g = blockIdx.x / PB2;
    int c = blockIdx.x - g * PB2;
    int cnt_g = g1[g]; if (cnt_g > CAPG1) cnt_g = CAPG1;
    int i0 = c * BCHK;
    int i1 = i0 + BCHK; if (i1 > cnt_g) i1 = cnt_g;
    if (i0 >= i1) return;
    if (tid < FPC) cF[tid] = 0;
    __syncthreads();
    const int* base = rec1 + (size_t)g * CAPG1;
    for (int i = i0 + tid; i < i1; i += 256) {
        int r = base[i];
        atomicAdd(&cF[(r >> 17) / NPB], 1);
    }
    __syncthreads();
    if (tid == 0) {
        int acc = 0;
        for (int f2 = 0; f2 < FPC; f2++) { sbF[f2] = acc; oF[f2] = acc; acc += cF[f2]; }
    }
    __syncthreads();
    if (tid < FPC) goF[tid] = (cF[tid] > 0) ? atomicAdd(&g2[g * FPC + tid], cF[tid]) : 0;
    __syncthreads();
    for (int i = i0 + tid; i < i1; i += 256) {
        int r = base[i];
        int p = atomicAdd(&oF[(r >> 17) / NPB], 1);
        stage[p] = r;
    }
    __syncthreads();
    for (int f2 = 0; f2 < FPC; f2++) {
        int cnt = cF[f2], b0 = goF[f2], sb0 = sbF[f2];
        int* out = rec2 + ((size_t)(g * FPC + f2)) * CAP;
        for (int i = tid; i < cnt; i += 256) {
            int p = b0 + i;
            if (p < CAP) out[p] = stage[sb0 + i];
        }
    }
}

__global__ __launch_bounds__(256) void k_build(const int* __restrict__ rec2,
                                               const int* __restrict__ g2,
                                               int* __restrict__ csr,
                                               int* __restrict__ rstart,
                                               int* __restrict__ rdeg) {
    __shared__ int lrec[CAP];
    __shared__ int lcsr[CAP];
    __shared__ int deg[NPB], pos[NPB + 1], pos2[NPB];
    int tid = threadIdx.x;
    int b = blockIdx.x;
    int f = b & (FPC - 1);
    int fbase = f * NPB;
    int cnt = g2[b]; if (cnt > CAP) cnt = CAP;
    for (int i = tid; i < cnt; i += 256) lrec[i] = rec2[(size_t)b * CAP + i];
    if (tid < NPB) deg[tid] = 0;
    __syncthreads();
    for (int i = tid; i < cnt; i += 256) atomicAdd(&deg[(lrec[i] >> 17) - fbase], 1);
    __syncthreads();
    if (tid == 0) {
        int acc = 0;
        for (int j = 0; j < NPB; j++) { pos[j] = acc; acc += deg[j]; }
        pos[NPB] = acc;
    }
    __syncthreads();
    int nbase = b * NPB;
    if (tid < NPB) {
        pos2[tid] = pos[tid];
        int n = nbase + tid;
        if (n < NN) { rstart[n] = b * CAP + pos[tid]; rdeg[n] = deg[tid]; }
    }
    __syncthreads();
    for (int i = tid; i < cnt; i += 256) {
        int r = lrec[i];
        int p = atomicAdd(&pos2[(r >> 17) - fbase], 1);
        lcsr[p] = r & 0x1FFFF;
    }
    __syncthreads();
    for (int i = tid; i < cnt; i += 256) csr[(size_t)b * CAP + i] = lcsr[i];
}

// ---------------- GAT transform (layer 0: raw input, DIN=5) ----------------
// Round-7: also precompute es = (bf16-rounded h) . a_s per node/head; store
// (es, ed) as float2 into esed[N][NH][2]. Removes the per-edge dot from
// k_aggregate (was ~33% of its VALU, recomputed deg~33 times per node).
__global__ void k_transform0(const void* x, const void* W, const void* ad_,
                             const float* __restrict__ prs,
                             const int* flag, unsigned short* hWb, float* esed) {
    __shared__ float sW[FIN * SHD];
    __shared__ float sad[SHD];
    __shared__ float sas[SHD];
    int tid = threadIdx.x;
    int f = flag[0];
    cp(sW, W, FIN * SHD, tid, 256, f);
    if (tid >= 192 && tid < 192 + SHD) sad[tid - 192] = ldw(ad_, tid - 192, f);
    if (tid >= 160 && tid < 160 + SHD) sas[tid - 160] = prs[tid - 160];
    __syncthreads();
    int n = blockIdx.x * 256 + tid;
    if (n >= NN) return;
    float xr[FIN];
    if (f) {
        const float* xp = (const float*)x + (size_t)n * FIN;
        for (int k = 0; k < FIN; k++) xr[k] = xp[k];
    } else {
        const bf16* xp = (const bf16*)x + (size_t)n * FIN;
        for (int k = 0; k < FIN; k++) xr[k] = b2f(xp[k]);
    }
    float o[SHD];
    for (int j = 0; j < SHD; j++) o[j] = 0.f;
    for (int k = 0; k < FIN; k++) {
        float xv = xr[k];
        for (int j = 0; j < SHD; j++) o[j] += xv * sW[k * SHD + j];
    }
    unsigned short us[SHD];
    for (int j = 0; j < SHD; j++) us[j] = f2b(o[j]);
    ushort4* row = (ushort4*)(hWb + (size_t)n * SHD);
    for (int q = 0; q < 8; q++) {
        ushort4 v; v.x = us[q*4]; v.y = us[q*4+1]; v.z = us[q*4+2]; v.w = us[q*4+3];
        row[q] = v;
    }
    for (int h = 0; h < NH; h++) {
        float e2 = 0.f;
        for (int c = 0; c < 4; c++) e2 += o[h * 4 + c] * sad[h * 4 + c];
        bf16 bb;
        float hb0, hb1, hb2, hb3;
        *reinterpret_cast<unsigned short*>(&bb) = us[h*4+0]; hb0 = b2f(bb);
        *reinterpret_cast<unsigned short*>(&bb) = us[h*4+1]; hb1 = b2f(bb);
        *reinterpret_cast<unsigned short*>(&bb) = us[h*4+2]; hb2 = b2f(bb);
        *reinterpret_cast<unsigned short*>(&bb) = us[h*4+3]; hb3 = b2f(bb);
        float es = (hb0 * sas[h*4+0] + hb2 * sas[h*4+2])
                 + (hb1 * sas[h*4+1] + hb3 * sas[h*4+3]);
        *(float2*)(esed + ((size_t)n * NH + h) * 2) = make_float2(es, e2);
    }
}

// ---------------- GAT transform (layers 1/2: f32 ws input, DIN=32) ----------
__global__ void k_transform1(const float* x, const void* W, const void* ad_,
                             const float* __restrict__ prs,
                             const int* flag, unsigned short* hWb, float* esed) {
    __shared__ float sW[SHD * SHD];
    __shared__ float sad[SHD];
    __shared__ float sas[SHD];
    int tid = threadIdx.x;
    int f = flag[0];
    cp(sW, W, SHD * SHD, tid, 256, f);
    if (tid >= 192 && tid < 192 + SHD) sad[tid - 192] = ldw(ad_, tid - 192, f);
    if (tid >= 160 && tid < 160 + SHD) sas[tid - 160] = prs[tid - 160];
    __syncthreads();
    int n = blockIdx.x * 256 + tid;
    if (n >= NN) return;
    float xr[SHD];
    const float4* xp4 = (const float4*)(x + (size_t)n * SHD);
#pragma unroll
    for (int q = 0; q < 8; q++) {
        float4 v = xp4[q];
        xr[q*4] = v.x; xr[q*4+1] = v.y; xr[q*4+2] = v.z; xr[q*4+3] = v.w;
    }
    float o[SHD];
    for (int j = 0; j < SHD; j++) o[j] = 0.f;
    for (int k = 0; k < SHD; k++) {
        float xv = xr[k];
        for (int j = 0; j < SHD; j++) o[j] += xv * sW[k * SHD + j];
    }
    unsigned short us[SHD];
    for (int j = 0; j < SHD; j++) us[j] = f2b(o[j]);
    ushort4* row = (ushort4*)(hWb + (size_t)n * SHD);
    for (int q = 0; q < 8; q++) {
        ushort4 v; v.x = us[q*4]; v.y = us[q*4+1]; v.z = us[q*4+2]; v.w = us[q*4+3];
        row[q] = v;
    }
    for (int h = 0; h < NH; h++) {
        float e2 = 0.f;
        for (int c = 0; c < 4; c++) e2 += o[h * 4 + c] * sad[h * 4 + c];
        bf16 bb;
        float hb0, hb1, hb2, hb3;
        *reinterpret_cast<unsigned short*>(&bb) = us[h*4+0]; hb0 = b2f(bb);
        *reinterpret_cast<unsigned short*>(&bb) = us[h*4+1]; hb1 = b2f(bb);
        *reinterpret_cast<unsigned short*>(&bb) = us[h*4+2]; hb2 = b2f(bb);
        *reinterpret_cast<unsigned short*>(&bb) = us[h*4+3]; hb3 = b2f(bb);
        float es = (hb0 * sas[h*4+0] + hb2 * sas[h*4+2])
                 + (hb1 * sas[h*4+1] + hb3 * sas[h*4+3]);
        *(float2*)(esed + ((size_t)n * NH + h) * 2) = make_float2(es, e2);
    }
}

// ---------------- GAT aggregation: 2 nodes/wave, 4-deep pipelined gather ----
// Round-7: per-edge attention logit uses precomputed es[src] (4B gather)
// instead of recomputing the a_s dot from the hWb row (~6 VALU/edge saved;
// round-6 PMC: VALUBusy ~70%, hbm 32% -> trade VALU for bandwidth headroom).
__global__ void k_aggregate(const int* __restrict__ rstart, const int* __restrict__ rdeg,
                            const int* __restrict__ csr,
                            const unsigned short* __restrict__ hWb,
                            const float* __restrict__ esed,
                            const float* __restrict__ prm,
                            float* __restrict__ out) {
    int gid = blockIdx.x * 256 + threadIdx.x;
    int lane = threadIdx.x & 63;
    int n = (gid >> 6) * 2 + (lane >> 5);
    if (n >= NN) return;
    int l32 = lane & 31;
    int h = l32 & 7, k = l32 >> 3;
    float ednh = esed[((size_t)n * NH + h) * 2 + 1];
    int base = rstart[n];
    int deg = rdeg[n];
    float den = 0.f;
    f32x2 acc01 = {0.f, 0.f}, acc23 = {0.f, 0.f};
    int t = k;
    int s0 = -1, s1 = -1, s2 = -1, s3 = -1;
    if (t <= deg)      s0 = (t == 0) ? n : __builtin_nontemporal_load(csr + base + t - 1);
    if (t + 4 <= deg)  s1 = __builtin_nontemporal_load(csr + base + t + 3);
    if (t + 8 <= deg)  s2 = __builtin_nontemporal_load(csr + base + t + 7);
    if (t + 12 <= deg) s3 = __builtin_nontemporal_load(csr + base + t + 11);
    while (s0 >= 0) {
        uint2 hv0 = *(const uint2*)(hWb + (size_t)s0 * SHD + h * 4);
        float ev0 = esed[((size_t)s0 * NH + h) * 2];
        bool b1 = (s1 >= 0), b2 = (s2 >= 0), b3 = (s3 >= 0);
        uint2 hv1, hv2, hv3;
        float ev1, ev2, ev3;
        if (b1) { hv1 = *(const uint2*)(hWb + (size_t)s1 * SHD + h * 4);
                  ev1 = esed[((size_t)s1 * NH + h) * 2]; }
        if (b2) { hv2 = *(const uint2*)(hWb + (size_t)s2 * SHD + h * 4);
                  ev2 = esed[((size_t)s2 * NH + h) * 2]; }
        if (b3) { hv3 = *(const uint2*)(hWb + (size_t)s3 * SHD + h * 4);
                  ev3 = esed[((size_t)s3 * NH + h) * 2]; }
        int tn = t + 16;
        int p0 = -1, p1 = -1, p2 = -1, p3 = -1;
        if (tn <= deg)      p0 = __builtin_nontemporal_load(csr + base + tn - 1);
        if (tn + 4 <= deg)  p1 = __builtin_nontemporal_load(csr + base + tn + 3);
        if (tn + 8 <= deg)  p2 = __builtin_nontemporal_load(csr + base + tn + 7);
        if (tn + 12 <= deg) p3 = __builtin_nontemporal_load(csr + base + tn + 11);
        {
            f32x2 h01, h23;
            h01.x = __uint_as_float(hv0.x << 16);
            h01.y = __uint_as_float(hv0.x & 0xffff0000u);
            h23.x = __uint_as_float(hv0.y << 16);
            h23.y = __uint_as_float(hv0.y & 0xffff0000u);
            float e = ev0 + ednh;
            e = fmaxf(e, 0.2f * e);
            float a = __expf(e);
            den += a;
            f32x2 av = {a, a};
            acc01 += av * h01;
            acc23 += av * h23;
        }
        if (b1) {
            f32x2 h01, h23;
            h01.x = __uint_as_float(hv1.x << 16);
            h01.y = __uint_as_float(hv1.x & 0xffff0000u);
            h23.x = __uint_as_float(hv1.y << 16);
            h23.y = __uint_as_float(hv1.y & 0xffff0000u);
            float e = ev1 + ednh;
            e = fmaxf(e, 0.2f * e);
            float a = __expf(e);
            den += a;
            f32x2 av = {a, a};
            acc01 += av * h01;
            acc23 += av * h23;
        }
        if (b2) {
            f32x2 h01, h23;
            h01.x = __uint_as_float(hv2.x << 16);
            h01.y = __uint_as_float(hv2.x & 0xffff0000u);
            h23.x = __uint_as_float(hv2.y << 16);
            h23.y = __uint_as_float(hv2.y & 0xffff0000u);
            float e = ev2 + ednh;
            e = fmaxf(e, 0.2f * e);
            float a = __expf(e);
            den += a;
            f32x2 av = {a, a};
            acc01 += av * h01;
            acc23 += av * h23;
        }
        if (b3) {
            f32x2 h01, h23;
            h01.x = __uint_as_float(hv3.x << 16);
            h01.y = __uint_as_float(hv3.x & 0xffff0000u);
            h23.x = __uint_as_float(hv3.y << 16);
            h23.y = __uint_as_float(hv3.y & 0xffff0000u);
            float e = ev3 + ednh;
            e = fmaxf(e, 0.2f * e);
            float a = __expf(e);
            den += a;
            f32x2 av = {a, a};
            acc01 += av * h01;
            acc23 += av * h23;
        }
        s0 = p0; s1 = p1; s2 = p2; s3 = p3; t = tn;
    }
    for (int off = 16; off >= 8; off >>= 1) {
        den      += __shfl_down(den, off, 32);
        acc01.x  += __shfl_down(acc01.x, off, 32);
        acc01.y  += __shfl_down(acc01.y, off, 32);
        acc23.x  += __shfl_down(acc23.x, off, 32);
        acc23.y  += __shfl_down(acc23.y, off, 32);
    }
    if (k == 0) {
        float inv = 1.f / (den + 1e-16f);
        float4 bv = *(const float4*)(prm + 32 + h * 4);
        float v0 = acc01.x * inv + bv.x;
        float v1 = acc01.y * inv + bv.y;
        float v2 = acc23.x * inv + bv.z;
        float v3 = acc23.y * inv + bv.w;
        v0 = (v0 > 0.f) ? v0 : expm1f(v0);
        v1 = (v1 > 0.f) ? v1 : expm1f(v1);
        v2 = (v2 > 0.f) ? v2 : expm1f(v2);
        v3 = (v3 > 0.f) ? v3 : expm1f(v3);
        *(float4*)(out + (size_t)n * SHD + h * 4) = make_float4(v0, v1, v2, v3);
    }
}

// ---------------- Temporal tail ---------------------------------------------
// Round-5-verified design (k_tail no longer in top-5). LSTM weights pinned
// in registers via asm("+v") (defeats remat, round-2 failure); L2 warm sweep
// and MLP matvecs use 8-wide batched loads (~8 loads per vmcnt drain).
template<typename T>
__device__ __forceinline__ void lstm_load_regs(
        const T* Wih0, const T* Whh0, const T* bih0, const T* bhh0,
        const T* Wih1, const T* Whh1, const T* bih1, const T* bhh1,
        const T* xin, int l, bool bl, float* xs,
        float& wa, float& ba, float& wb, float& bb, float& ba2, float& bb2,
        float* Wa, float* Wb, float* Ua, float* Va, float* Ub, float* Vb) {
#pragma unroll
    for (int t = 0; t < SEQL; t++) xs[t] = cvf(xin[t]);
    wa = cvf(Wih0[l]);
    ba = cvf(bih0[l]) + cvf(bhh0[l]);
    wb = bl ? cvf(Wih0[64 + l]) : 0.f;
    bb = bl ? (cvf(bih0[64 + l]) + cvf(bhh0[64 + l])) : 0.f;
    ba2 = cvf(bih1[l]) + cvf(bhh1[l]);
    bb2 = bl ? (cvf(bih1[64 + l]) + cvf(bhh1[64 + l])) : 0.f;
#pragma unroll
    for (int j = 0; j < 21; j++) {
        Wa[j] = cvf(Whh0[l * 21 + j]);
        Wb[j] = bl ? cvf(Whh0[(64 + l) * 21 + j]) : 0.f;
        Ua[j] = cvf(Wih1[l * 21 + j]);
        Va[j] = cvf(Whh1[l * 21 + j]);
        Ub[j] = bl ? cvf(Wih1[(64 + l) * 21 + j]) : 0.f;
        Vb[j] = bl ? cvf(Whh1[(64 + l) * 21 + j]) : 0.f;
    }
}

// L2 warm sweep: values discarded; 8 independent uint4 loads per drain.
__device__ __forceinline__ void warm_sweep(const void* p, int nbytes, int t2) {
    const uint4* s = (const uint4*)p;
    int nv = nbytes >> 4;
    unsigned acc = 0;
    for (int i = t2; i < nv; i += 1024) {
        uint4 v0 = s[i];
        uint4 v1 = (i + 128 < nv) ? s[i + 128] : make_uint4(0,0,0,0);
        uint4 v2 = (i + 256 < nv) ? s[i + 256] : make_uint4(0,0,0,0);
        uint4 v3 = (i + 384 < nv) ? s[i + 384] : make_uint4(0,0,0,0);
        uint4 v4 = (i + 512 < nv) ? s[i + 512] : make_uint4(0,0,0,0);
        uint4 v5 = (i + 640 < nv) ? s[i + 640] : make_uint4(0,0,0,0);
        uint4 v6 = (i + 768 < nv) ? s[i + 768] : make_uint4(0,0,0,0);
        uint4 v7 = (i + 896 < nv) ? s[i + 896] : make_uint4(0,0,0,0);
        acc ^= v0.x ^ v1.x ^ v2.x ^ v3.x ^ v4.x ^ v5.x ^ v6.x ^ v7.x;
    }
    asm volatile("" :: "v"(acc));
}

// matvec with 8-wide batched weight loads; accumulation order identical to
// the plain sequential loop (k2 ascending, one add per k2).
template<typename T>
__device__ __forceinline__ float matvec_t(const T* W, const float* vin,
                                          float bias, int n, int col, int ncol) {
    float acc = bias;
    int k2 = 0;
    for (; k2 + 8 <= n; k2 += 8) {
        float w0 = cvf(W[(k2 + 0) * ncol + col]);
        float w1 = cvf(W[(k2 + 1) * ncol + col]);
        float w2 = cvf(W[(k2 + 2) * ncol + col]);
        float w3 = cvf(W[(k2 + 3) * ncol + col]);
        float w4 = cvf(W[(k2 + 4) * ncol + col]);
        float w5 = cvf(W[(k2 + 5) * ncol + col]);
        float w6 = cvf(W[(k2 + 6) * ncol + col]);
        float w7 = cvf(W[(k2 + 7) * ncol + col]);
        acc += vin[k2 + 0] * w0; acc += vin[k2 + 1] * w1;
        acc += vin[k2 + 2] * w2; acc += vin[k2 + 3] * w3;
        acc += vin[k2 + 4] * w4; acc += vin[k2 + 5] * w5;
        acc += vin[k2 + 6] * w6; acc += vin[k2 + 7] * w7;
    }
    for (; k2 < n; k2++) acc += vin[k2] * cvf(W[k2 * ncol + col]);
    return acc;
}
__device__ __forceinline__ float matvec(const void* W, const float* vin,
                                        float bias, int n, int col, int ncol, int f) {
    return f ? matvec_t<float>((const float*)W, vin, bias, n, col, ncol)
             : matvec_t<bf16>((const bf16*)W, vin, bias, n, col, ncol);
}

__global__ __launch_bounds__(256, 1)
void k_tail(const void* trend, const void* seasonal, const void* residual,
                       const void* cv, const int* tgtp,
                       const void* tWih0, const void* tWhh0, const void* tbih0, const void* tbhh0,
                       const void* tWih1, const void* tWhh1, const void* tbih1, const void* tbhh1,
                       const void* sWih0, const void* sWhh0, const void* sbih0, const void* sbhh0,
                       const void* sWih1, const void* sWhh1, const void* sbih1, const void* sbhh1,
                       const void* res_W, const void* res_b,
                       const void* pg_W, const void* pg_b,
                       const void* f1_W, const void* f1_b,
                       const void* ln_g, const void* ln_b,
                       const void* f2_W, const void* f2_b,
                       const void* f3_W, const void* f3_b,
                       const int* flag, const float* A, void* out) {
    __shared__ __align__(16) float SH1[2][24];
    __shared__ __align__(16) float SH2[2][24];
    __shared__ float comb[97];
    __shared__ float gf[96];
    __shared__ float h1v[64];
    __shared__ float h2s[32];
    __shared__ float sbias[336];  // pg_b@0 f1_b@96 f2_b@160 f3_b@192 ln_g@208 ln_b@272
    __shared__ float stats[2];
    const int tid = threadIdx.x;
    const int f = flag[0];
    const int w = tid >> 6, l = tid & 63;

    if (tid < 96) {
        if (tid < 48) SH1[tid / 24][tid % 24] = 0.f;
        else { int u = tid - 48; SH2[u / 24][u % 24] = 0.f; }
    }
    __syncthreads();

    if (w < 2) {
        // ---- cascaded 2-layer LSTM, one per wave, weights pinned in regs ----
        const void* Wih0 = w ? sWih0 : tWih0;
        const void* Whh0 = w ? sWhh0 : tWhh0;
        const void* bih0 = w ? sbih0 : tbih0;
        const void* bhh0 = w ? sbhh0 : tbhh0;
        const void* Wih1 = w ? sWih1 : tWih1;
        const void* Whh1 = w ? sWhh1 : tWhh1;
        const void* bih1 = w ? sbih1 : tbih1;
        const void* bhh1 = w ? sbhh1 : tbhh1;
        const void* xin  = w ? seasonal : trend;
        const bool bl = (l < 20);
        float xs[SEQL];
        float wa, ba, wb, bb, ba2, bb2;
        float Wa[21], Wb[21], Ua[21], Va[21], Ub[21], Vb[21];
        if (f) {
            lstm_load_regs<float>((const float*)Wih0, (const float*)Whh0,
                (const float*)bih0, (const float*)bhh0,
                (const float*)Wih1, (const float*)Whh1,
                (const float*)bih1, (const float*)bhh1,
                (const float*)xin, l, bl, xs, wa, ba, wb, bb, ba2, bb2,
                Wa, Wb, Ua, Va, Ub, Vb);
        } else {
            lstm_load_regs<bf16>((const bf16*)Wih0, (const bf16*)Whh0,
                (const bf16*)bih0, (const bf16*)bhh0,
                (const bf16*)Wih1, (const bf16*)Whh1,
                (const bf16*)bih1, (const bf16*)bhh1,
                (const bf16*)xin, l, bl, xs, wa, ba, wb, bb, ba2, bb2,
                Wa, Wb, Ua, Va, Ub, Vb);
        }
        // PIN: make every weight opaque to the rematerializer. Round-2
        // showed RA prefers re-loading from global inside the loop (~900cy
        // per value per step) over keeping 126 regs live, even with
        // launch_bounds(256,1). asm-defined values cannot be remat'd.
#pragma unroll
        for (int j = 0; j < 21; j++) {
            asm volatile("" : "+v"(Wa[j]), "+v"(Wb[j]));
            asm volatile("" : "+v"(Ua[j]), "+v"(Va[j]));
            asm volatile("" : "+v"(Ub[j]), "+v"(Vb[j]));
        }
#pragma unroll
        for (int t = 0; t < SEQL; t++) asm volatile("" : "+v"(xs[t]));
        asm volatile("" : "+v"(wa), "+v"(ba));
        asm volatile("" : "+v"(wb), "+v"(bb));
        asm volatile("" : "+v"(ba2), "+v"(bb2));

        float h1r = 0.f, c1 = 0.f, h2r = 0.f, c2 = 0.f;
#pragma unroll 1
        for (int t = 0; t < SEQL; t++) {
            // layer 1
            float aa = ba + xs[t] * wa;
            float ab = bb + xs[t] * wb;
#pragma unroll
            for (int q = 0; q < 5; q++) {
                float4 v = *(const float4*)&SH1[w][q * 4];
                aa += v.x * Wa[q*4];   ab += v.x * Wb[q*4];
                aa += v.y * Wa[q*4+1]; ab += v.y * Wb[q*4+1];
                aa += v.z * Wa[q*4+2]; ab += v.z * Wb[q*4+2];
                aa += v.w * Wa[q*4+3]; ab += v.w * Wb[q*4+3];
            }
            { float v20 = SH1[w][20]; aa += v20 * Wa[20]; ab += v20 * Wb[20]; }
            float fj = __shfl(aa, 21 + l);
            float gj = __shfl(aa, 42 + l);
            float oa = __shfl(aa, 63);
            float ob = __shfl(ab, (l == 0) ? 0 : (l - 1));
            float oj = (l == 0) ? oa : ob;
            if (l < 21) {
                c1 = sigm(fj) * c1 + sigm(aa) * tanhf(gj);
                h1r = sigm(oj) * tanhf(c1);
                SH1[w][l] = h1r;
            }
            __threadfence_block();
            // layer 2 (consumes fresh h1)
            float a2 = ba2, b2v = bb2;
#pragma unroll
            for (int q = 0; q < 5; q++) {
                float4 u = *(const float4*)&SH1[w][q * 4];
                float4 v = *(const float4*)&SH2[w][q * 4];
                a2  += u.x * Ua[q*4]   + v.x * Va[q*4];
                b2v += u.x * Ub[q*4]   + v.x * Vb[q*4];
                a2  += u.y * Ua[q*4+1] + v.y * Va[q*4+1];
                b2v += u.y * Ub[q*4+1] + v.y * Vb[q*4+1];
                a2  += u.z * Ua[q*4+2] + v.z * Va[q*4+2];
                b2v += u.z * Ub[q*4+2] + v.z * Vb[q*4+2];
                a2  += u.w * Ua[q*4+3] + v.w * Va[q*4+3];
                b2v += u.w * Ub[q*4+3] + v.w * Vb[q*4+3];
            }
            { float u20 = SH1[w][20], v20 = SH2[w][20];
              a2  += u20 * Ua[20] + v20 * Va[20];
              b2v += u20 * Ub[20] + v20 * Vb[20]; }
            float fj2 = __shfl(a2, 21 + l);
            float gj2 = __shfl(a2, 42 + l);
            float oa2 = __shfl(a2, 63);
            float ob2 = __shfl(b2v, (l == 0) ? 0 : (l - 1));
            float oj2 = (l == 0) ? oa2 : ob2;
            if (l < 21) {
                c2 = sigm(fj2) * c2 + sigm(a2) * tanhf(gj2);
                h2r = sigm(oj2) * tanhf(c2);
                SH2[w][l] = h2r;
            }
            __threadfence_block();
        }
        if (l < 21) comb[(w == 0 ? 32 : 53) + l] = h2r;
    } else {
        // ---- waves 2-3: small jobs + pipelined L2 warm of MLP weights ----
        int t2 = tid - 128;   // 0..127
        if (t2 < TRH)
            comb[74 + t2] = relu_nan(ldw(residual, SEQL - 1, f) * ldw(res_W, t2, f)
                                     + ldw(res_b, t2, f));
        if (t2 == TRH) comb[96] = ldw(cv, 0, f);
        if (t2 >= 32 && t2 < 64) {
            int tgt = tgtp[0];
            comb[t2 - 32] = A[(size_t)tgt * SHD + (t2 - 32)];
        }
        for (int i = t2; i < 336; i += 128) {
            float v;
            if (i < 96)       v = ldw(pg_b, i, f);
            else if (i < 160) v = ldw(f1_b, i - 96, f);
            else if (i < 192) v = ldw(f2_b, i - 160, f);
            else if (i < 206) v = ldw(f3_b, i - 192, f);
            else if (i < 208) v = 0.f;
            else if (i < 272) v = ldw(ln_g, i - 208, f);
            else              v = ldw(ln_b, i - 272, f);
            sbias[i] = v;
        }
        int esz = f ? 4 : 2;
        warm_sweep(pg_W, 9312 * esz, t2);
        warm_sweep(f1_W, 6144 * esz, t2);
        warm_sweep(f2_W, 2048 * esz, t2);
        warm_sweep(f3_W,  448 * esz, t2);
    }
    __syncthreads();

    // gate: gf = comb * sigm(comb @ pg_W + pg_b)   (weights from L2)
    if (tid < 96)
        gf[tid] = comb[tid] * sigm(matvec(pg_W, comb, sbias[tid], 97, tid, 96, f));
    __syncthreads();
    if (tid < 64)
        h1v[tid] = matvec(f1_W, gf, sbias[96 + tid], 96, tid, 64, f);
    __syncthreads();
    if (tid == 0) {
        float mu = 0.f;
        for (int j = 0; j < 64; j++) mu += h1v[j];
        mu /= 64.f;
        float var = 0.f;
        for (int j = 0; j < 64; j++) { float d = h1v[j] - mu; var += d * d; }
        var /= 64.f;
        stats[0] = mu; stats[1] = rsqrtf(var + 1e-5f);
    }
    __syncthreads();
    if (tid < 64)
        h1v[tid] = relu_nan((h1v[tid] - stats[0]) * stats[1] * sbias[208 + tid] + sbias[272 + tid]);
    __syncthreads();
    if (tid < 32)
        h2s[tid] = relu_nan(matvec(f2_W, h1v, sbias[160 + tid], 64, tid, 32, f));
    __syncthreads();
    if (tid < SEQL) {
        float acc = matvec(f3_W, h2s, sbias[192 + tid], 32, tid, 14, f);
        if (acc != acc) acc = 3333.0f;
        if (f) ((float*)out)[tid] = acc;
        else   ((bf16*)out)[tid] = __float2bfloat16(acc);
    }
}

// ---------------- host helpers ----------------
static inline unsigned short h_f2bf(float f) {
    union { float f; unsigned u; } x; x.f = f;
    return (unsigned short)(x.u >> 16);
}
static unsigned short g_diag[SEQL];

// ---------------- launch ----------------
extern "C" void kernel_launch(void* const* d_in, const int* in_sizes, int n_in,
                              void* d_out, int out_size, void* d_ws, size_t ws_size,
                              hipStream_t stream) {
    const int* ei  = (const int*)d_in[1];
    const int* tgt = (const int*)d_in[6];

    const size_t HWB  = sizeof(unsigned short) * (size_t)NN * SHD;
    const size_t EDB  = sizeof(float) * (size_t)NN * NH * 2;
    const size_t AB   = sizeof(float) * (size_t)NN * SHD;
    const size_t CSRB = sizeof(int) * (size_t)NBUK * CAP;
    const size_t NEED = 256 + 1024 + sizeof(int) * (size_t)(NC + NBUK + 2 * NN + 32)
                      + CSRB + 512 + HWB + EDB + AB;
    if (ws_size < NEED ||
        sizeof(int) * (size_t)NC * CAPG1 > CSRB ||
        sizeof(int) * (size_t)NBUK * CAP > HWB + EDB + AB) {
        for (int i = 0; i < SEQL; i++) g_diag[i] = h_f2bf(7777.0f);
        hipMemcpyAsync(d_out, g_diag, SEQL * sizeof(unsigned short),
                       hipMemcpyHostToDevice, stream);
        return;
    }

    char* p = (char*)d_ws;
    int*   flag = (int*)p;   p += 256;
    float* prm  = (float*)p; p += 1024;
    int* g1     = (int*)p; p += sizeof(int) * NC;
    int* g2     = (int*)p; p += sizeof(int) * NBUK;
    int* rstart = (int*)p; p += sizeof(int) * NN;
    int* rdeg   = (int*)p; p += sizeof(int) * (NN + 32);
    int* csr    = (int*)p; p += CSRB;
    p = (char*)(((uintptr_t)p + 255) & ~(uintptr_t)255);
    unsigned short* hWb = (unsigned short*)p; p += HWB;
    float* esed = (float*)p; p += EDB;
    float* A  = (float*)p; p += AB;
    int* rec1 = csr;
    int* rec2 = (int*)hWb;

    dim3 b256(256);
    dim3 gN((NN + 255) / 256);
    dim3 gA2(((NN + 1) / 2 * 64 + 255) / 256);

    PatternAwareSTGAT_94489281309_kernel<<<dim3(1), dim3(64), 0, stream>>>(
        (const unsigned int*)d_in[0], flag,
        d_in[8], d_in[10], d_in[12], d_in[14], d_in[16], d_in[18], prm);

    hipMemsetAsync(g1, 0, sizeof(int) * (NC + NBUK), stream);
    k_p1<<<dim3(NBC1), b256, 0, stream>>>(ei, g1, rec1);
    k_p2<<<dim3(NC * PB2), b256, 0, stream>>>(rec1, g1, g2, rec2);
    k_build<<<dim3(NBUK), b256, 0, stream>>>(rec2, g2, csr, rstart, rdeg);

    k_transform0<<<gN, b256, 0, stream>>>(d_in[0], d_in[7], d_in[9], prm, flag, hWb, esed);
    k_aggregate<<<gA2, b256, 0, stream>>>(rstart, rdeg, csr, hWb, esed, prm, A);
    k_transform1<<<gN, b256, 0, stream>>>(A, d_in[11], d_in[13], prm + 64, flag, hWb, esed);
    k_aggregate<<<gA2, b256, 0, stream>>>(rstart, rdeg, csr, hWb, esed, prm + 64, A);
    k_transform1<<<gN, b256, 0, stream>>>(A, d_in[15], d_in[17], prm + 128, flag, hWb, esed);
    k_aggregate<<<gA2, b256, 0, stream>>>(rstart, rdeg, csr, hWb, esed, prm + 128, A);

    k_tail<<<dim3(1), b256, 0, stream>>>(
        d_in[2], d_in[3], d_in[4], d_in[5], tgt,
        d_in[19], d_in[20], d_in[21], d_in[22],
        d_in[23], d_in[24], d_in[25], d_in[26],
        d_in[27], d_in[28], d_in[29], d_in[30],
        d_in[31], d_in[32], d_in[33], d_in[34],
        d_in[35], d_in[36],
        d_in[37], d_in[38],
        d_in[39], d_in[40],
        d_in[41], d_in[42],
        d_in[43], d_in[44],
        d_in[45], d_in[46],
        flag, A, d_out);
}

// Round 8
// 411.079 us; speedup vs baseline: 1.3644x; 1.3644x over previous
//
#include <hip/hip_runtime.h>
#include <hip/hip_bf16.h>
#include <stdint.h>
#include <math.h>

#define NN   100000
#define EE   3200000
#define FIN  5
#define SHD  32
#define NH   8
#define TCH  21
#define TRH  22
#define SEQL 14

#define NPB   98
#define FPC   64
#define NC    16
#define NBUK  (NC * FPC)
#define CSZ   (NPB * FPC)
#define CAP   3712
#define CAPG1 208896
#define BCHK  4096
#define NBC1  ((EE + BCHK - 1) / BCHK)
#define PB2   ((CAPG1 + BCHK - 1) / BCHK)

typedef __hip_bfloat16 bf16;
typedef __attribute__((ext_vector_type(2))) float f32x2;

__device__ __forceinline__ float b2f(bf16 v) { return __bfloat162float(v); }
__device__ __forceinline__ float sigm(float x) { return 1.f / (1.f + __expf(-x)); }
__device__ __forceinline__ float ldw(const void* p, int i, int f) {
    return f ? ((const float*)p)[i] : __bfloat162float(((const bf16*)p)[i]);
}
__device__ __forceinline__ float relu_nan(float v) {
    return (v == v) ? ((v > 0.f) ? v : 0.f) : v;
}
__device__ __forceinline__ unsigned short f2b(float v) {
    bf16 b = __float2bfloat16(v);
    return *reinterpret_cast<unsigned short*>(&b);
}
__device__ __forceinline__ float cvf(float v) { return v; }
__device__ __forceinline__ float cvf(bf16 v) { return __bfloat162float(v); }
__device__ __forceinline__ void cp(float* dst, const void* src, int n,
                                   int t0, int stride, int f) {
    if (f) {
        const float* s = (const float*)src;
        for (int i = t0; i < n; i += stride) dst[i] = s[i];
    } else {
        const bf16* s = (const bf16*)src;
        for (int i = t0; i < n; i += stride) dst[i] = b2f(s[i]);
    }
}

// ---- dtype detect + f32 param pre-convert (identifier-named, 1 wave) ------
__global__ void PatternAwareSTGAT_94489281309_kernel(const unsigned int* xw, int* flag,
        const void* as0, const void* b0, const void* as1, const void* b1,
        const void* as2, const void* b2, float* prm) {
    int tid = threadIdx.x;   // 64
    int sane = 0;
    for (int i = 0; i < 64; i++) {
        unsigned int lo = xw[i] & 0xFFFFu;
        int e = (int)((lo >> 7) & 0xFF);
        if (e >= 110 && e <= 135) sane++;
    }
    int f = (sane >= 32) ? 0 : 1;
    if (tid == 0) flag[0] = f;
    const void* asp[3] = {as0, as1, as2};
    const void* bp[3]  = {b0, b1, b2};
    for (int l = 0; l < 3; l++)
        prm[l * 64 + tid] = (tid < 32) ? ldw(asp[l], tid, f) : ldw(bp[l], tid - 32, f);
}

// ---------------- CSR build: two-level LDS-staged counting sort --------------
__global__ __launch_bounds__(256) void k_p1(const int* __restrict__ ei,
                                            int* __restrict__ g1,
                                            int* __restrict__ rec1) {
    __shared__ int stage[BCHK];
    __shared__ int c16[NC], o16[NC], go[NC], sb[NC];
    int tid = threadIdx.x;
    if (tid < NC) c16[tid] = 0;
    __syncthreads();
    int e0 = blockIdx.x * BCHK;
    int e1 = e0 + BCHK; if (e1 > EE) e1 = EE;
    for (int e = e0 + tid; e < e1; e += 256) {
        int d = __builtin_nontemporal_load(ei + EE + e);
        atomicAdd(&c16[d / CSZ], 1);
    }
    __syncthreads();
    if (tid == 0) {
        int acc = 0;
        for (int g = 0; g < NC; g++) { sb[g] = acc; o16[g] = acc; acc += c16[g]; }
    }
    __syncthreads();
    if (tid < NC) go[tid] = (c16[tid] > 0) ? atomicAdd(&g1[tid], c16[tid]) : 0;
    __syncthreads();
    for (int e = e0 + tid; e < e1; e += 256) {
        int s = __builtin_nontemporal_load(ei + e);
        int d = __builtin_nontemporal_load(ei + EE + e);
        int g = d / CSZ;
        int p = atomicAdd(&o16[g], 1);
        stage[p] = s | ((d - g * CSZ) << 17);
    }
    __syncthreads();
    for (int g = 0; g < NC; g++) {
        int cnt = c16[g], base = go[g], sbase = sb[g];
        int* out = rec1 + (size_t)g * CAPG1;
        for (int i = tid; i < cnt; i += 256) {
            int p = base + i;
            if (p < CAPG1) out[p] = stage[sbase + i];
        }
    }
}

__global__ __launch_bounds__(256) void k_p2(const int* __restrict__ rec1,
                                            const int* __restrict__ g1,
                                            int* __restrict__ g2,
                                            int* __restrict__ rec2) {
    __shared__ int stage[BCHK];
    __shared__ int cF[FPC], oF[FPC], goF[FPC], sbF[FPC];
    int tid = threadIdx.x;
    int g = blockIdx.x / PB2;
    int c = blockIdx.x - g * PB2;
    int cnt_g = g1[g]; if (cnt_g > CAPG1) cnt_g = CAPG1;
    int i0 = c * BCHK;
    int i1 = i0 + BCHK; if (i1 > cnt_g) i1 = cnt_g;
    if (i0 >= i1) return;
    if (tid < FPC) cF[tid] = 0;
    __syncthreads();
    const int* base = rec1 + (size_t)g * CAPG1;
    for (int i = i0 + tid; i < i1; i += 256) {
        int r = base[i];
        atomicAdd(&cF[(r >> 17) / NPB], 1);
    }
    __syncthreads();
    if (tid == 0) {
        int acc = 0;
        for (int f2 = 0; f2 < FPC; f2++) { sbF[f2] = acc; oF[f2] = acc; acc += cF[f2]; }
    }
    __syncthreads();
    if (tid < FPC) goF[tid] = (cF[tid] > 0) ? atomicAdd(&g2[g * FPC + tid], cF[tid]) : 0;
    __syncthreads();
    for (int i = i0 + tid; i < i1; i += 256) {
        int r = base[i];
        int p = atomicAdd(&oF[(r >> 17) / NPB], 1);
        stage[p] = r;
    }
    __syncthreads();
    for (int f2 = 0; f2 < FPC; f2++) {
        int cnt = cF[f2], b0 = goF[f2], sb0 = sbF[f2];
        int* out = rec2 + ((size_t)(g * FPC + f2)) * CAP;
        for (int i = tid; i < cnt; i += 256) {
            int p = b0 + i;
            if (p < CAP) out[p] = stage[sb0 + i];
        }
    }
}

__global__ __launch_bounds__(256) void k_build(const int* __restrict__ rec2,
                                               const int* __restrict__ g2,
                                               int* __restrict__ csr,
                                               int* __restrict__ rstart,
                                               int* __restrict__ rdeg) {
    __shared__ int lrec[CAP];
    __shared__ int lcsr[CAP];
    __shared__ int deg[NPB], pos[NPB + 1], pos2[NPB];
    int tid = threadIdx.x;
    int b = blockIdx.x;
    int f = b & (FPC - 1);
    int fbase = f * NPB;
    int cnt = g2[b]; if (cnt > CAP) cnt = CAP;
    for (int i = tid; i < cnt; i += 256) lrec[i] = rec2[(size_t)b * CAP + i];
    if (tid < NPB) deg[tid] = 0;
    __syncthreads();
    for (int i = tid; i < cnt; i += 256) atomicAdd(&deg[(lrec[i] >> 17) - fbase], 1);
    __syncthreads();
    if (tid == 0) {
        int acc = 0;
        for (int j = 0; j < NPB; j++) { pos[j] = acc; acc += deg[j]; }
        pos[NPB] = acc;
    }
    __syncthreads();
    int nbase = b * NPB;
    if (tid < NPB) {
        pos2[tid] = pos[tid];
        int n = nbase + tid;
        if (n < NN) { rstart[n] = b * CAP + pos[tid]; rdeg[n] = deg[tid]; }
    }
    __syncthreads();
    for (int i = tid; i < cnt; i += 256) {
        int r = lrec[i];
        int p = atomicAdd(&pos2[(r >> 17) - fbase], 1);
        lcsr[p] = r & 0x1FFFF;
    }
    __syncthreads();
    for (int i = tid; i < cnt; i += 256) csr[(size_t)b * CAP + i] = lcsr[i];
}

// ---------------- GAT transform (layer 0: raw input, DIN=5) ----------------
__global__ void k_transform0(const void* x, const void* W, const void* ad_,
                             const int* flag, unsigned short* hWb, float* ed) {
    __shared__ float sW[FIN * SHD];
    __shared__ float sad[SHD];
    int tid = threadIdx.x;
    int f = flag[0];
    cp(sW, W, FIN * SHD, tid, 256, f);
    if (tid >= 192 && tid < 192 + SHD) sad[tid - 192] = ldw(ad_, tid - 192, f);
    __syncthreads();
    int n = blockIdx.x * 256 + tid;
    if (n >= NN) return;
    float xr[FIN];
    if (f) {
        const float* xp = (const float*)x + (size_t)n * FIN;
        for (int k = 0; k < FIN; k++) xr[k] = xp[k];
    } else {
        const bf16* xp = (const bf16*)x + (size_t)n * FIN;
        for (int k = 0; k < FIN; k++) xr[k] = b2f(xp[k]);
    }
    float o[SHD];
    for (int j = 0; j < SHD; j++) o[j] = 0.f;
    for (int k = 0; k < FIN; k++) {
        float xv = xr[k];
        for (int j = 0; j < SHD; j++) o[j] += xv * sW[k * SHD + j];
    }
    ushort4* row = (ushort4*)(hWb + (size_t)n * SHD);
    for (int q = 0; q < 8; q++) {
        ushort4 v; v.x = f2b(o[q*4]); v.y = f2b(o[q*4+1]); v.z = f2b(o[q*4+2]); v.w = f2b(o[q*4+3]);
        row[q] = v;
    }
    for (int h = 0; h < NH; h++) {
        float e2 = 0.f;
        for (int c = 0; c < 4; c++) e2 += o[h * 4 + c] * sad[h * 4 + c];
        ed[(size_t)n * NH + h] = e2;
    }
}

// ---------------- GAT transform (layers 1/2: f32 ws input, DIN=32) ----------
// Round-6: x-row read via float4 (8x16B instead of 32 scalar loads).
__global__ void k_transform1(const float* x, const void* W, const void* ad_,
                             const int* flag, unsigned short* hWb, float* ed) {
    __shared__ float sW[SHD * SHD];
    __shared__ float sad[SHD];
    int tid = threadIdx.x;
    int f = flag[0];
    cp(sW, W, SHD * SHD, tid, 256, f);
    if (tid >= 192 && tid < 192 + SHD) sad[tid - 192] = ldw(ad_, tid - 192, f);
    __syncthreads();
    int n = blockIdx.x * 256 + tid;
    if (n >= NN) return;
    float xr[SHD];
    const float4* xp4 = (const float4*)(x + (size_t)n * SHD);
#pragma unroll
    for (int q = 0; q < 8; q++) {
        float4 v = xp4[q];
        xr[q*4] = v.x; xr[q*4+1] = v.y; xr[q*4+2] = v.z; xr[q*4+3] = v.w;
    }
    float o[SHD];
    for (int j = 0; j < SHD; j++) o[j] = 0.f;
    for (int k = 0; k < SHD; k++) {
        float xv = xr[k];
        for (int j = 0; j < SHD; j++) o[j] += xv * sW[k * SHD + j];
    }
    ushort4* row = (ushort4*)(hWb + (size_t)n * SHD);
    for (int q = 0; q < 8; q++) {
        ushort4 v; v.x = f2b(o[q*4]); v.y = f2b(o[q*4+1]); v.z = f2b(o[q*4+2]); v.w = f2b(o[q*4+3]);
        row[q] = v;
    }
    for (int h = 0; h < NH; h++) {
        float e2 = 0.f;
        for (int c = 0; c < 4; c++) e2 += o[h * 4 + c] * sad[h * 4 + c];
        ed[(size_t)n * NH + h] = e2;
    }
}

// ---------------- GAT aggregation: 2 nodes/wave, 6-deep pipelined gather ----
// Round-8: REVERT of round-7 es-precompute (FETCH 104->303MB, 46->87us —
// a second random 64B line per edge at ~50% L2 hit costs far more than the
// ~6 VALU it saves; es must share h's cache line or not exist). This is the
// round-6 kernel (46.4us, VALUBusy ~70%) with pipeline depth 4 -> 6.
// Per-k-lane edge order stays ascending t (k, k+4, ...) -> bitwise identical.
__global__ void k_aggregate(const int* __restrict__ rstart, const int* __restrict__ rdeg,
                            const int* __restrict__ csr,
                            const unsigned short* __restrict__ hWb,
                            const float* __restrict__ ed,
                            const float* __restrict__ prm,
                            float* __restrict__ out) {
    int gid = blockIdx.x * 256 + threadIdx.x;
    int lane = threadIdx.x & 63;
    int n = (gid >> 6) * 2 + (lane >> 5);
    if (n >= NN) return;
    int l32 = lane & 31;
    int h = l32 & 7, k = l32 >> 3;
    float4 asv = *(const float4*)(prm + h * 4);
    float ednh = ed[(size_t)n * NH + h];
    int base = rstart[n];
    int deg = rdeg[n];
    float den = 0.f;
    f32x2 acc01 = {0.f, 0.f}, acc23 = {0.f, 0.f};
    int t = k;
    int s0 = -1, s1 = -1, s2 = -1, s3 = -1, s4 = -1, s5 = -1;
    if (t <= deg)      s0 = (t == 0) ? n : __builtin_nontemporal_load(csr + base + t - 1);
    if (t + 4 <= deg)  s1 = __builtin_nontemporal_load(csr + base + t + 3);
    if (t + 8 <= deg)  s2 = __builtin_nontemporal_load(csr + base + t + 7);
    if (t + 12 <= deg) s3 = __builtin_nontemporal_load(csr + base + t + 11);
    if (t + 16 <= deg) s4 = __builtin_nontemporal_load(csr + base + t + 15);
    if (t + 20 <= deg) s5 = __builtin_nontemporal_load(csr + base + t + 19);
    while (s0 >= 0) {
        uint2 hv0 = *(const uint2*)(hWb + (size_t)s0 * SHD + h * 4);
        bool b1 = (s1 >= 0), b2 = (s2 >= 0), b3 = (s3 >= 0), b4 = (s4 >= 0), b5 = (s5 >= 0);
        uint2 hv1, hv2, hv3, hv4, hv5;
        if (b1) hv1 = *(const uint2*)(hWb + (size_t)s1 * SHD + h * 4);
        if (b2) hv2 = *(const uint2*)(hWb + (size_t)s2 * SHD + h * 4);
        if (b3) hv3 = *(const uint2*)(hWb + (size_t)s3 * SHD + h * 4);
        if (b4) hv4 = *(const uint2*)(hWb + (size_t)s4 * SHD + h * 4);
        if (b5) hv5 = *(const uint2*)(hWb + (size_t)s5 * SHD + h * 4);
        int tn = t + 24;
        int p0 = -1, p1 = -1, p2 = -1, p3 = -1, p4 = -1, p5 = -1;
        if (tn <= deg)      p0 = __builtin_nontemporal_load(csr + base + tn - 1);
        if (tn + 4 <= deg)  p1 = __builtin_nontemporal_load(csr + base + tn + 3);
        if (tn + 8 <= deg)  p2 = __builtin_nontemporal_load(csr + base + tn + 7);
        if (tn + 12 <= deg) p3 = __builtin_nontemporal_load(csr + base + tn + 11);
        if (tn + 16 <= deg) p4 = __builtin_nontemporal_load(csr + base + tn + 15);
        if (tn + 20 <= deg) p5 = __builtin_nontemporal_load(csr + base + tn + 19);
        {
            f32x2 h01, h23;
            h01.x = __uint_as_float(hv0.x << 16);
            h01.y = __uint_as_float(hv0.x & 0xffff0000u);
            h23.x = __uint_as_float(hv0.y << 16);
            h23.y = __uint_as_float(hv0.y & 0xffff0000u);
            f32x2 d2 = h01 * (f32x2){asv.x, asv.y} + h23 * (f32x2){asv.z, asv.w};
            float e = d2.x + d2.y + ednh;
            e = fmaxf(e, 0.2f * e);
            float a = __expf(e);
            den += a;
            f32x2 av = {a, a};
            acc01 += av * h01;
            acc23 += av * h23;
        }
        if (b1) {
            f32x2 h01, h23;
            h01.x = __uint_as_float(hv1.x << 16);
            h01.y = __uint_as_float(hv1.x & 0xffff0000u);
            h23.x = __uint_as_float(hv1.y << 16);
            h23.y = __uint_as_float(hv1.y & 0xffff0000u);
            f32x2 d2 = h01 * (f32x2){asv.x, asv.y} + h23 * (f32x2){asv.z, asv.w};
            float e = d2.x + d2.y + ednh;
            e = fmaxf(e, 0.2f * e);
            float a = __expf(e);
            den += a;
            f32x2 av = {a, a};
            acc01 += av * h01;
            acc23 += av * h23;
        }
        if (b2) {
            f32x2 h01, h23;
            h01.x = __uint_as_float(hv2.x << 16);
            h01.y = __uint_as_float(hv2.x & 0xffff0000u);
            h23.x = __uint_as_float(hv2.y << 16);
            h23.y = __uint_as_float(hv2.y & 0xffff0000u);
            f32x2 d2 = h01 * (f32x2){asv.x, asv.y} + h23 * (f32x2){asv.z, asv.w};
            float e = d2.x + d2.y + ednh;
            e = fmaxf(e, 0.2f * e);
            float a = __expf(e);
            den += a;
            f32x2 av = {a, a};
            acc01 += av * h01;
            acc23 += av * h23;
        }
        if (b3) {
            f32x2 h01, h23;
            h01.x = __uint_as_float(hv3.x << 16);
            h01.y = __uint_as_float(hv3.x & 0xffff0000u);
            h23.x = __uint_as_float(hv3.y << 16);
            h23.y = __uint_as_float(hv3.y & 0xffff0000u);
            f32x2 d2 = h01 * (f32x2){asv.x, asv.y} + h23 * (f32x2){asv.z, asv.w};
            float e = d2.x + d2.y + ednh;
            e = fmaxf(e, 0.2f * e);
            float a = __expf(e);
            den += a;
            f32x2 av = {a, a};
            acc01 += av * h01;
            acc23 += av * h23;
        }
        if (b4) {
            f32x2 h01, h23;
            h01.x = __uint_as_float(hv4.x << 16);
            h01.y = __uint_as_float(hv4.x & 0xffff0000u);
            h23.x = __uint_as_float(hv4.y << 16);
            h23.y = __uint_as_float(hv4.y & 0xffff0000u);
            f32x2 d2 = h01 * (f32x2){asv.x, asv.y} + h23 * (f32x2){asv.z, asv.w};
            float e = d2.x + d2.y + ednh;
            e = fmaxf(e, 0.2f * e);
            float a = __expf(e);
            den += a;
            f32x2 av = {a, a};
            acc01 += av * h01;
            acc23 += av * h23;
        }
        if (b5) {
            f32x2 h01, h23;
            h01.x = __uint_as_float(hv5.x << 16);
            h01.y = __uint_as_float(hv5.x & 0xffff0000u);
            h23.x = __uint_as_float(hv5.y << 16);
            h23.y = __uint_as_float(hv5.y & 0xffff0000u);
            f32x2 d2 = h01 * (f32x2){asv.x, asv.y} + h23 * (f32x2){asv.z, asv.w};
            float e = d2.x + d2.y + ednh;
            e = fmaxf(e, 0.2f * e);
            float a = __expf(e);
            den += a;
            f32x2 av = {a, a};
            acc01 += av * h01;
            acc23 += av * h23;
        }
        s0 = p0; s1 = p1; s2 = p2; s3 = p3; s4 = p4; s5 = p5; t = tn;
    }
    for (int off = 16; off >= 8; off >>= 1) {
        den      += __shfl_down(den, off, 32);
        acc01.x  += __shfl_down(acc01.x, off, 32);
        acc01.y  += __shfl_down(acc01.y, off, 32);
        acc23.x  += __shfl_down(acc23.x, off, 32);
        acc23.y  += __shfl_down(acc23.y, off, 32);
    }
    if (k == 0) {
        float inv = 1.f / (den + 1e-16f);
        float4 bv = *(const float4*)(prm + 32 + h * 4);
        float v0 = acc01.x * inv + bv.x;
        float v1 = acc01.y * inv + bv.y;
        float v2 = acc23.x * inv + bv.z;
        float v3 = acc23.y * inv + bv.w;
        v0 = (v0 > 0.f) ? v0 : expm1f(v0);
        v1 = (v1 > 0.f) ? v1 : expm1f(v1);
        v2 = (v2 > 0.f) ? v2 : expm1f(v2);
        v3 = (v3 > 0.f) ? v3 : expm1f(v3);
        *(float4*)(out + (size_t)n * SHD + h * 4) = make_float4(v0, v1, v2, v3);
    }
}

// ---------------- Temporal tail ---------------------------------------------
// Round-5-verified design (k_tail no longer in top-5). LSTM weights pinned
// in registers via asm("+v") (defeats remat, round-2 failure); L2 warm sweep
// and MLP matvecs use 8-wide batched loads (~8 loads per vmcnt drain).
template<typename T>
__device__ __forceinline__ void lstm_load_regs(
        const T* Wih0, const T* Whh0, const T* bih0, const T* bhh0,
        const T* Wih1, const T* Whh1, const T* bih1, const T* bhh1,
        const T* xin, int l, bool bl, float* xs,
        float& wa, float& ba, float& wb, float& bb, float& ba2, float& bb2,
        float* Wa, float* Wb, float* Ua, float* Va, float* Ub, float* Vb) {
#pragma unroll
    for (int t = 0; t < SEQL; t++) xs[t] = cvf(xin[t]);
    wa = cvf(Wih0[l]);
    ba = cvf(bih0[l]) + cvf(bhh0[l]);
    wb = bl ? cvf(Wih0[64 + l]) : 0.f;
    bb = bl ? (cvf(bih0[64 + l]) + cvf(bhh0[64 + l])) : 0.f;
    ba2 = cvf(bih1[l]) + cvf(bhh1[l]);
    bb2 = bl ? (cvf(bih1[64 + l]) + cvf(bhh1[64 + l])) : 0.f;
#pragma unroll
    for (int j = 0; j < 21; j++) {
        Wa[j] = cvf(Whh0[l * 21 + j]);
        Wb[j] = bl ? cvf(Whh0[(64 + l) * 21 + j]) : 0.f;
        Ua[j] = cvf(Wih1[l * 21 + j]);
        Va[j] = cvf(Whh1[l * 21 + j]);
        Ub[j] = bl ? cvf(Wih1[(64 + l) * 21 + j]) : 0.f;
        Vb[j] = bl ? cvf(Whh1[(64 + l) * 21 + j]) : 0.f;
    }
}

// L2 warm sweep: values discarded; 8 independent uint4 loads per drain.
__device__ __forceinline__ void warm_sweep(const void* p, int nbytes, int t2) {
    const uint4* s = (const uint4*)p;
    int nv = nbytes >> 4;
    unsigned acc = 0;
    for (int i = t2; i < nv; i += 1024) {
        uint4 v0 = s[i];
        uint4 v1 = (i + 128 < nv) ? s[i + 128] : make_uint4(0,0,0,0);
        uint4 v2 = (i + 256 < nv) ? s[i + 256] : make_uint4(0,0,0,0);
        uint4 v3 = (i + 384 < nv) ? s[i + 384] : make_uint4(0,0,0,0);
        uint4 v4 = (i + 512 < nv) ? s[i + 512] : make_uint4(0,0,0,0);
        uint4 v5 = (i + 640 < nv) ? s[i + 640] : make_uint4(0,0,0,0);
        uint4 v6 = (i + 768 < nv) ? s[i + 768] : make_uint4(0,0,0,0);
        uint4 v7 = (i + 896 < nv) ? s[i + 896] : make_uint4(0,0,0,0);
        acc ^= v0.x ^ v1.x ^ v2.x ^ v3.x ^ v4.x ^ v5.x ^ v6.x ^ v7.x;
    }
    asm volatile("" :: "v"(acc));
}

// matvec with 8-wide batched weight loads; accumulation order identical to
// the plain sequential loop (k2 ascending, one add per k2).
template<typename T>
__device__ __forceinline__ float matvec_t(const T* W, const float* vin,
                                          float bias, int n, int col, int ncol) {
    float acc = bias;
    int k2 = 0;
    for (; k2 + 8 <= n; k2 += 8) {
        float w0 = cvf(W[(k2 + 0) * ncol + col]);
        float w1 = cvf(W[(k2 + 1) * ncol + col]);
        float w2 = cvf(W[(k2 + 2) * ncol + col]);
        float w3 = cvf(W[(k2 + 3) * ncol + col]);
        float w4 = cvf(W[(k2 + 4) * ncol + col]);
        float w5 = cvf(W[(k2 + 5) * ncol + col]);
        float w6 = cvf(W[(k2 + 6) * ncol + col]);
        float w7 = cvf(W[(k2 + 7) * ncol + col]);
        acc += vin[k2 + 0] * w0; acc += vin[k2 + 1] * w1;
        acc += vin[k2 + 2] * w2; acc += vin[k2 + 3] * w3;
        acc += vin[k2 + 4] * w4; acc += vin[k2 + 5] * w5;
        acc += vin[k2 + 6] * w6; acc += vin[k2 + 7] * w7;
    }
    for (; k2 < n; k2++) acc += vin[k2] * cvf(W[k2 * ncol + col]);
    return acc;
}
__device__ __forceinline__ float matvec(const void* W, const float* vin,
                                        float bias, int n, int col, int ncol, int f) {
    return f ? matvec_t<float>((const float*)W, vin, bias, n, col, ncol)
             : matvec_t<bf16>((const bf16*)W, vin, bias, n, col, ncol);
}

__global__ __launch_bounds__(256, 1)
void k_tail(const void* trend, const void* seasonal, const void* residual,
                       const void* cv, const int* tgtp,
                       const void* tWih0, const void* tWhh0, const void* tbih0, const void* tbhh0,
                       const void* tWih1, const void* tWhh1, const void* tbih1, const void* tbhh1,
                       const void* sWih0, const void* sWhh0, const void* sbih0, const void* sbhh0,
                       const void* sWih1, const void* sWhh1, const void* sbih1, const void* sbhh1,
                       const void* res_W, const void* res_b,
                       const void* pg_W, const void* pg_b,
                       const void* f1_W, const void* f1_b,
                       const void* ln_g, const void* ln_b,
                       const void* f2_W, const void* f2_b,
                       const void* f3_W, const void* f3_b,
                       const int* flag, const float* A, void* out) {
    __shared__ __align__(16) float SH1[2][24];
    __shared__ __align__(16) float SH2[2][24];
    __shared__ float comb[97];
    __shared__ float gf[96];
    __shared__ float h1v[64];
    __shared__ float h2s[32];
    __shared__ float sbias[336];  // pg_b@0 f1_b@96 f2_b@160 f3_b@192 ln_g@208 ln_b@272
    __shared__ float stats[2];
    const int tid = threadIdx.x;
    const int f = flag[0];
    const int w = tid >> 6, l = tid & 63;

    if (tid < 96) {
        if (tid < 48) SH1[tid / 24][tid % 24] = 0.f;
        else { int u = tid - 48; SH2[u / 24][u % 24] = 0.f; }
    }
    __syncthreads();

    if (w < 2) {
        // ---- cascaded 2-layer LSTM, one per wave, weights pinned in regs ----
        const void* Wih0 = w ? sWih0 : tWih0;
        const void* Whh0 = w ? sWhh0 : tWhh0;
        const void* bih0 = w ? sbih0 : tbih0;
        const void* bhh0 = w ? sbhh0 : tbhh0;
        const void* Wih1 = w ? sWih1 : tWih1;
        const void* Whh1 = w ? sWhh1 : tWhh1;
        const void* bih1 = w ? sbih1 : tbih1;
        const void* bhh1 = w ? sbhh1 : tbhh1;
        const void* xin  = w ? seasonal : trend;
        const bool bl = (l < 20);
        float xs[SEQL];
        float wa, ba, wb, bb, ba2, bb2;
        float Wa[21], Wb[21], Ua[21], Va[21], Ub[21], Vb[21];
        if (f) {
            lstm_load_regs<float>((const float*)Wih0, (const float*)Whh0,
                (const float*)bih0, (const float*)bhh0,
                (const float*)Wih1, (const float*)Whh1,
                (const float*)bih1, (const float*)bhh1,
                (const float*)xin, l, bl, xs, wa, ba, wb, bb, ba2, bb2,
                Wa, Wb, Ua, Va, Ub, Vb);
        } else {
            lstm_load_regs<bf16>((const bf16*)Wih0, (const bf16*)Whh0,
                (const bf16*)bih0, (const bf16*)bhh0,
                (const bf16*)Wih1, (const bf16*)Whh1,
                (const bf16*)bih1, (const bf16*)bhh1,
                (const bf16*)xin, l, bl, xs, wa, ba, wb, bb, ba2, bb2,
                Wa, Wb, Ua, Va, Ub, Vb);
        }
        // PIN: make every weight opaque to the rematerializer. Round-2
        // showed RA prefers re-loading from global inside the loop (~900cy
        // per value per step) over keeping 126 regs live, even with
        // launch_bounds(256,1). asm-defined values cannot be remat'd.
#pragma unroll
        for (int j = 0; j < 21; j++) {
            asm volatile("" : "+v"(Wa[j]), "+v"(Wb[j]));
            asm volatile("" : "+v"(Ua[j]), "+v"(Va[j]));
            asm volatile("" : "+v"(Ub[j]), "+v"(Vb[j]));
        }
#pragma unroll
        for (int t = 0; t < SEQL; t++) asm volatile("" : "+v"(xs[t]));
        asm volatile("" : "+v"(wa), "+v"(ba));
        asm volatile("" : "+v"(wb), "+v"(bb));
        asm volatile("" : "+v"(ba2), "+v"(bb2));

        float h1r = 0.f, c1 = 0.f, h2r = 0.f, c2 = 0.f;
#pragma unroll 1
        for (int t = 0; t < SEQL; t++) {
            // layer 1
            float aa = ba + xs[t] * wa;
            float ab = bb + xs[t] * wb;
#pragma unroll
            for (int q = 0; q < 5; q++) {
                float4 v = *(const float4*)&SH1[w][q * 4];
                aa += v.x * Wa[q*4];   ab += v.x * Wb[q*4];
                aa += v.y * Wa[q*4+1]; ab += v.y * Wb[q*4+1];
                aa += v.z * Wa[q*4+2]; ab += v.z * Wb[q*4+2];
                aa += v.w * Wa[q*4+3]; ab += v.w * Wb[q*4+3];
            }
            { float v20 = SH1[w][20]; aa += v20 * Wa[20]; ab += v20 * Wb[20]; }
            float fj = __shfl(aa, 21 + l);
            float gj = __shfl(aa, 42 + l);
            float oa = __shfl(aa, 63);
            float ob = __shfl(ab, (l == 0) ? 0 : (l - 1));
            float oj = (l == 0) ? oa : ob;
            if (l < 21) {
                c1 = sigm(fj) * c1 + sigm(aa) * tanhf(gj);
                h1r = sigm(oj) * tanhf(c1);
                SH1[w][l] = h1r;
            }
            __threadfence_block();
            // layer 2 (consumes fresh h1)
            float a2 = ba2, b2v = bb2;
#pragma unroll
            for (int q = 0; q < 5; q++) {
                float4 u = *(const float4*)&SH1[w][q * 4];
                float4 v = *(const float4*)&SH2[w][q * 4];
                a2  += u.x * Ua[q*4]   + v.x * Va[q*4];
                b2v += u.x * Ub[q*4]   + v.x * Vb[q*4];
                a2  += u.y * Ua[q*4+1] + v.y * Va[q*4+1];
                b2v += u.y * Ub[q*4+1] + v.y * Vb[q*4+1];
                a2  += u.z * Ua[q*4+2] + v.z * Va[q*4+2];
                b2v += u.z * Ub[q*4+2] + v.z * Vb[q*4+2];
                a2  += u.w * Ua[q*4+3] + v.w * Va[q*4+3];
                b2v += u.w * Ub[q*4+3] + v.w * Vb[q*4+3];
            }
            { float u20 = SH1[w][20], v20 = SH2[w][20];
              a2  += u20 * Ua[20] + v20 * Va[20];
              b2v += u20 * Ub[20] + v20 * Vb[20]; }
            float fj2 = __shfl(a2, 21 + l);
            float gj2 = __shfl(a2, 42 + l);
            float oa2 = __shfl(a2, 63);
            float ob2 = __shfl(b2v, (l == 0) ? 0 : (l - 1));
            float oj2 = (l == 0) ? oa2 : ob2;
            if (l < 21) {
                c2 = sigm(fj2) * c2 + sigm(a2) * tanhf(gj2);
                h2r = sigm(oj2) * tanhf(c2);
                SH2[w][l] = h2r;
            }
            __threadfence_block();
        }
        if (l < 21) comb[(w == 0 ? 32 : 53) + l] = h2r;
    } else {
        // ---- waves 2-3: small jobs + pipelined L2 warm of MLP weights ----
        int t2 = tid - 128;   // 0..127
        if (t2 < TRH)
            comb[74 + t2] = relu_nan(ldw(residual, SEQL - 1, f) * ldw(res_W, t2, f)
                                     + ldw(res_b, t2, f));
        if (t2 == TRH) comb[96] = ldw(cv, 0, f);
        if (t2 >= 32 && t2 < 64) {
            int tgt = tgtp[0];
            comb[t2 - 32] = A[(size_t)tgt * SHD + (t2 - 32)];
        }
        for (int i = t2; i < 336; i += 128) {
            float v;
            if (i < 96)       v = ldw(pg_b, i, f);
            else if (i < 160) v = ldw(f1_b, i - 96, f);
            else if (i < 192) v = ldw(f2_b, i - 160, f);
            else if (i < 206) v = ldw(f3_b, i - 192, f);
            else if (i < 208) v = 0.f;
            else if (i < 272) v = ldw(ln_g, i - 208, f);
            else              v = ldw(ln_b, i - 272, f);
            sbias[i] = v;
        }
        int esz = f ? 4 : 2;
        warm_sweep(pg_W, 9312 * esz, t2);
        warm_sweep(f1_W, 6144 * esz, t2);
        warm_sweep(f2_W, 2048 * esz, t2);
        warm_sweep(f3_W,  448 * esz, t2);
    }
    __syncthreads();

    // gate: gf = comb * sigm(comb @ pg_W + pg_b)   (weights from L2)
    if (tid < 96)
        gf[tid] = comb[tid] * sigm(matvec(pg_W, comb, sbias[tid], 97, tid, 96, f));
    __syncthreads();
    if (tid < 64)
        h1v[tid] = matvec(f1_W, gf, sbias[96 + tid], 96, tid, 64, f);
    __syncthreads();
    if (tid == 0) {
        float mu = 0.f;
        for (int j = 0; j < 64; j++) mu += h1v[j];
        mu /= 64.f;
        float var = 0.f;
        for (int j = 0; j < 64; j++) { float d = h1v[j] - mu; var += d * d; }
        var /= 64.f;
        stats[0] = mu; stats[1] = rsqrtf(var + 1e-5f);
    }
    __syncthreads();
    if (tid < 64)
        h1v[tid] = relu_nan((h1v[tid] - stats[0]) * stats[1] * sbias[208 + tid] + sbias[272 + tid]);
    __syncthreads();
    if (tid < 32)
        h2s[tid] = relu_nan(matvec(f2_W, h1v, sbias[160 + tid], 64, tid, 32, f));
    __syncthreads();
    if (tid < SEQL) {
        float acc = matvec(f3_W, h2s, sbias[192 + tid], 32, tid, 14, f);
        if (acc != acc) acc = 3333.0f;
        if (f) ((float*)out)[tid] = acc;
        else   ((bf16*)out)[tid] = __float2bfloat16(acc);
    }
}

// ---------------- host helpers ----------------
static inline unsigned short h_f2bf(float f) {
    union { float f; unsigned u; } x; x.f = f;
    return (unsigned short)(x.u >> 16);
}
static unsigned short g_diag[SEQL];

// ---------------- launch ----------------
extern "C" void kernel_launch(void* const* d_in, const int* in_sizes, int n_in,
                              void* d_out, int out_size, void* d_ws, size_t ws_size,
                              hipStream_t stream) {
    const int* ei  = (const int*)d_in[1];
    const int* tgt = (const int*)d_in[6];

    const size_t HWB  = sizeof(unsigned short) * (size_t)NN * SHD;
    const size_t EDB  = sizeof(float) * (size_t)NN * NH;
    const size_t AB   = sizeof(float) * (size_t)NN * SHD;
    const size_t CSRB = sizeof(int) * (size_t)NBUK * CAP;
    const size_t NEED = 256 + 1024 + sizeof(int) * (size_t)(NC + NBUK + 2 * NN + 32)
                      + CSRB + 512 + HWB + EDB + AB;
    if (ws_size < NEED ||
        sizeof(int) * (size_t)NC * CAPG1 > CSRB ||
        sizeof(int) * (size_t)NBUK * CAP > HWB + EDB + AB) {
        for (int i = 0; i < SEQL; i++) g_diag[i] = h_f2bf(7777.0f);
        hipMemcpyAsync(d_out, g_diag, SEQL * sizeof(unsigned short),
                       hipMemcpyHostToDevice, stream);
        return;
    }

    char* p = (char*)d_ws;
    int*   flag = (int*)p;   p += 256;
    float* prm  = (float*)p; p += 1024;
    int* g1     = (int*)p; p += sizeof(int) * NC;
    int* g2     = (int*)p; p += sizeof(int) * NBUK;
    int* rstart = (int*)p; p += sizeof(int) * NN;
    int* rdeg   = (int*)p; p += sizeof(int) * (NN + 32);
    int* csr    = (int*)p; p += CSRB;
    p = (char*)(((uintptr_t)p + 255) & ~(uintptr_t)255);
    unsigned short* hWb = (unsigned short*)p; p += HWB;
    float* ed = (float*)p; p += EDB;
    float* A  = (float*)p; p += AB;
    int* rec1 = csr;
    int* rec2 = (int*)hWb;

    dim3 b256(256);
    dim3 gN((NN + 255) / 256);
    dim3 gA2(((NN + 1) / 2 * 64 + 255) / 256);

    PatternAwareSTGAT_94489281309_kernel<<<dim3(1), dim3(64), 0, stream>>>(
        (const unsigned int*)d_in[0], flag,
        d_in[8], d_in[10], d_in[12], d_in[14], d_in[16], d_in[18], prm);

    hipMemsetAsync(g1, 0, sizeof(int) * (NC + NBUK), stream);
    k_p1<<<dim3(NBC1), b256, 0, stream>>>(ei, g1, rec1);
    k_p2<<<dim3(NC * PB2), b256, 0, stream>>>(rec1, g1, g2, rec2);
    k_build<<<dim3(NBUK), b256, 0, stream>>>(rec2, g2, csr, rstart, rdeg);

    k_transform0<<<gN, b256, 0, stream>>>(d_in[0], d_in[7], d_in[9], flag, hWb, ed);
    k_aggregate<<<gA2, b256, 0, stream>>>(rstart, rdeg, csr, hWb, ed, prm, A);
    k_transform1<<<gN, b256, 0, stream>>>(A, d_in[11], d_in[13], flag, hWb, ed);
    k_aggregate<<<gA2, b256, 0, stream>>>(rstart, rdeg, csr, hWb, ed, prm + 64, A);
    k_transform1<<<gN, b256, 0, stream>>>(A, d_in[15], d_in[17], flag, hWb, ed);
    k_aggregate<<<gA2, b256, 0, stream>>>(rstart, rdeg, csr, hWb, ed, prm + 128, A);

    k_tail<<<dim3(1), b256, 0, stream>>>(
        d_in[2], d_in[3], d_in[4], d_in[5], tgt,
        d_in[19], d_in[20], d_in[21], d_in[22],
        d_in[23], d_in[24], d_in[25], d_in[26],
        d_in[27], d_in[28], d_in[29], d_in[30],
        d_in[31], d_in[32], d_in[33], d_in[34],
        d_in[35], d_in[36],
        d_in[37], d_in[38],
        d_in[39], d_in[40],
        d_in[41], d_in[42],
        d_in[43], d_in[44],
        d_in[45], d_in[46],
        flag, A, d_out);
}

// Round 9
// 299.885 us; speedup vs baseline: 1.8702x; 1.3708x over previous
//
#include <hip/hip_runtime.h>
#include <hip/hip_bf16.h>
#include <stdint.h>
#include <math.h>

#define NN   100000
#define EE   3200000
#define FIN  5
#define SHD  32
#define NH   8
#define TCH  21
#define TRH  22
#define SEQL 14

#define NPB   98
#define FPC   64
#define NC    16
#define NBUK  (NC * FPC)
#define CSZ   (NPB * FPC)
#define CAP   3712
#define CAPG1 208896
#define BCHK  4096
#define NBC1  ((EE + BCHK - 1) / BCHK)
#define PB2   ((CAPG1 + BCHK - 1) / BCHK)

// frontier list capacities (dependency-cone pruning, round-9)
#define EC1   256     // F1 = in-neighbors(tgt)+self; E[deg]=33, cap 7-sigma safe
#define EC2   4096    // F2 = union of F1's in-neighborhoods (~1.2k expected)

typedef __hip_bfloat16 bf16;
typedef __attribute__((ext_vector_type(2))) float f32x2;

__device__ __forceinline__ float b2f(bf16 v) { return __bfloat162float(v); }
__device__ __forceinline__ float sigm(float x) { return 1.f / (1.f + __expf(-x)); }
__device__ __forceinline__ float ldw(const void* p, int i, int f) {
    return f ? ((const float*)p)[i] : __bfloat162float(((const bf16*)p)[i]);
}
__device__ __forceinline__ float relu_nan(float v) {
    return (v == v) ? ((v > 0.f) ? v : 0.f) : v;
}
__device__ __forceinline__ unsigned short f2b(float v) {
    bf16 b = __float2bfloat16(v);
    return *reinterpret_cast<unsigned short*>(&b);
}
__device__ __forceinline__ float cvf(float v) { return v; }
__device__ __forceinline__ float cvf(bf16 v) { return __bfloat162float(v); }
__device__ __forceinline__ void cp(float* dst, const void* src, int n,
                                   int t0, int stride, int f) {
    if (f) {
        const float* s = (const float*)src;
        for (int i = t0; i < n; i += stride) dst[i] = s[i];
    } else {
        const bf16* s = (const bf16*)src;
        for (int i = t0; i < n; i += stride) dst[i] = b2f(s[i]);
    }
}

// ---- dtype detect + f32 param pre-convert (identifier-named, 1 wave) ------
__global__ void PatternAwareSTGAT_94489281309_kernel(const unsigned int* xw, int* flag,
        const void* as0, const void* b0, const void* as1, const void* b1,
        const void* as2, const void* b2, float* prm) {
    int tid = threadIdx.x;   // 64
    int sane = 0;
    for (int i = 0; i < 64; i++) {
        unsigned int lo = xw[i] & 0xFFFFu;
        int e = (int)((lo >> 7) & 0xFF);
        if (e >= 110 && e <= 135) sane++;
    }
    int f = (sane >= 32) ? 0 : 1;
    if (tid == 0) flag[0] = f;
    const void* asp[3] = {as0, as1, as2};
    const void* bp[3]  = {b0, b1, b2};
    for (int l = 0; l < 3; l++)
        prm[l * 64 + tid] = (tid < 32) ? ldw(asp[l], tid, f) : ldw(bp[l], tid - 32, f);
}

// ---------------- CSR build: two-level LDS-staged counting sort --------------
__global__ __launch_bounds__(256) void k_p1(const int* __restrict__ ei,
                                            int* __restrict__ g1,
                                            int* __restrict__ rec1) {
    __shared__ int stage[BCHK];
    __shared__ int c16[NC], o16[NC], go[NC], sb[NC];
    int tid = threadIdx.x;
    if (tid < NC) c16[tid] = 0;
    __syncthreads();
    int e0 = blockIdx.x * BCHK;
    int e1 = e0 + BCHK; if (e1 > EE) e1 = EE;
    for (int e = e0 + tid; e < e1; e += 256) {
        int d = __builtin_nontemporal_load(ei + EE + e);
        atomicAdd(&c16[d / CSZ], 1);
    }
    __syncthreads();
    if (tid == 0) {
        int acc = 0;
        for (int g = 0; g < NC; g++) { sb[g] = acc; o16[g] = acc; acc += c16[g]; }
    }
    __syncthreads();
    if (tid < NC) go[tid] = (c16[tid] > 0) ? atomicAdd(&g1[tid], c16[tid]) : 0;
    __syncthreads();
    for (int e = e0 + tid; e < e1; e += 256) {
        int s = __builtin_nontemporal_load(ei + e);
        int d = __builtin_nontemporal_load(ei + EE + e);
        int g = d / CSZ;
        int p = atomicAdd(&o16[g], 1);
        stage[p] = s | ((d - g * CSZ) << 17);
    }
    __syncthreads();
    for (int g = 0; g < NC; g++) {
        int cnt = c16[g], base = go[g], sbase = sb[g];
        int* out = rec1 + (size_t)g * CAPG1;
        for (int i = tid; i < cnt; i += 256) {
            int p = base + i;
            if (p < CAPG1) out[p] = stage[sbase + i];
        }
    }
}

__global__ __launch_bounds__(256) void k_p2(const int* __restrict__ rec1,
                                            const int* __restrict__ g1,
                                            int* __restrict__ g2,
                                            int* __restrict__ rec2) {
    __shared__ int stage[BCHK];
    __shared__ int cF[FPC], oF[FPC], goF[FPC], sbF[FPC];
    int tid = threadIdx.x;
    int g = blockIdx.x / PB2;
    int c = blockIdx.x - g * PB2;
    int cnt_g = g1[g]; if (cnt_g > CAPG1) cnt_g = CAPG1;
    int i0 = c * BCHK;
    int i1 = i0 + BCHK; if (i1 > cnt_g) i1 = cnt_g;
    if (i0 >= i1) return;
    if (tid < FPC) cF[tid] = 0;
    __syncthreads();
    const int* base = rec1 + (size_t)g * CAPG1;
    for (int i = i0 + tid; i < i1; i += 256) {
        int r = base[i];
        atomicAdd(&cF[(r >> 17) / NPB], 1);
    }
    __syncthreads();
    if (tid == 0) {
        int acc = 0;
        for (int f2 = 0; f2 < FPC; f2++) { sbF[f2] = acc; oF[f2] = acc; acc += cF[f2]; }
    }
    __syncthreads();
    if (tid < FPC) goF[tid] = (cF[tid] > 0) ? atomicAdd(&g2[g * FPC + tid], cF[tid]) : 0;
    __syncthreads();
    for (int i = i0 + tid; i < i1; i += 256) {
        int r = base[i];
        int p = atomicAdd(&oF[(r >> 17) / NPB], 1);
        stage[p] = r;
    }
    __syncthreads();
    for (int f2 = 0; f2 < FPC; f2++) {
        int cnt = cF[f2], b0 = goF[f2], sb0 = sbF[f2];
        int* out = rec2 + ((size_t)(g * FPC + f2)) * CAP;
        for (int i = tid; i < cnt; i += 256) {
            int p = b0 + i;
            if (p < CAP) out[p] = stage[sb0 + i];
        }
    }
}

__global__ __launch_bounds__(256) void k_build(const int* __restrict__ rec2,
                                               const int* __restrict__ g2,
                                               int* __restrict__ csr,
                                               int* __restrict__ rstart,
                                               int* __restrict__ rdeg) {
    __shared__ int lrec[CAP];
    __shared__ int lcsr[CAP];
    __shared__ int deg[NPB], pos[NPB + 1], pos2[NPB];
    int tid = threadIdx.x;
    int b = blockIdx.x;
    int f = b & (FPC - 1);
    int fbase = f * NPB;
    int cnt = g2[b]; if (cnt > CAP) cnt = CAP;
    for (int i = tid; i < cnt; i += 256) lrec[i] = rec2[(size_t)b * CAP + i];
    if (tid < NPB) deg[tid] = 0;
    __syncthreads();
    for (int i = tid; i < cnt; i += 256) atomicAdd(&deg[(lrec[i] >> 17) - fbase], 1);
    __syncthreads();
    if (tid == 0) {
        int acc = 0;
        for (int j = 0; j < NPB; j++) { pos[j] = acc; acc += deg[j]; }
        pos[NPB] = acc;
    }
    __syncthreads();
    int nbase = b * NPB;
    if (tid < NPB) {
        pos2[tid] = pos[tid];
        int n = nbase + tid;
        if (n < NN) { rstart[n] = b * CAP + pos[tid]; rdeg[n] = deg[tid]; }
    }
    __syncthreads();
    for (int i = tid; i < cnt; i += 256) {
        int r = lrec[i];
        int p = atomicAdd(&pos2[(r >> 17) - fbase], 1);
        lcsr[p] = r & 0x1FFFF;
    }
    __syncthreads();
    for (int i = tid; i < cnt; i += 256) csr[(size_t)b * CAP + i] = lcsr[i];
}

// ---------------- Frontier build (round-9 dependency-cone pruning) ----------
// Only A[tgt] of the final GAT layer is consumed (tail reads one row). GAT is
// 1-hop local, so: layer-3 agg needs {tgt}; layer-3 transform + layer-2 agg
// need F1 = N_in(tgt)+self; layer-2 transform + layer-1 agg need
// F2 = union of F1's (N_in + self). Layer-1 transform (t0) stays full.
__global__ void k_front(const int* __restrict__ rstart, const int* __restrict__ rdeg,
                        const int* __restrict__ csr, const int* __restrict__ tgtp,
                        int* __restrict__ l1, int* __restrict__ c1,
                        int* __restrict__ l3, int* __restrict__ c3) {
    int tgt = tgtp[0];
    int d = rdeg[tgt]; if (d > EC1 - 1) d = EC1 - 1;
    int b = rstart[tgt];
    for (int i = threadIdx.x; i < d; i += 64) l1[i] = csr[b + i];
    if (threadIdx.x == 0) { l1[d] = tgt; c1[0] = d + 1; l3[0] = tgt; c3[0] = 1; }
}

// one F1 entry per 64-thread block; append its in-neighbors + self to l2.
// List order / duplicates are benign: per-node aggregate math is independent
// and deterministic; duplicate entries write identical bytes.
__global__ void k_front2(const int* __restrict__ rstart, const int* __restrict__ rdeg,
                         const int* __restrict__ csr,
                         const int* __restrict__ l1, const int* __restrict__ c1,
                         int* __restrict__ l2, int* __restrict__ c2) {
    int i = blockIdx.x;
    if (i >= c1[0]) return;
    int s = l1[i];
    int d = rdeg[s];
    int b = rstart[s];
    int base = 0;
    if (threadIdx.x == 0) base = atomicAdd(c2, d + 1);
    base = __shfl(base, 0);
    for (int j = threadIdx.x; j < d; j += 64) {
        int p = base + j;
        if (p < EC2) l2[p] = csr[b + j];
    }
    if (threadIdx.x == 0 && base + d < EC2) l2[base + d] = s;
}

// ---------------- GAT transform (layer 0: raw input, DIN=5, full N) ---------
__global__ void k_transform0(const void* x, const void* W, const void* ad_,
                             const int* flag, unsigned short* hWb, float* ed) {
    __shared__ float sW[FIN * SHD];
    __shared__ float sad[SHD];
    int tid = threadIdx.x;
    int f = flag[0];
    cp(sW, W, FIN * SHD, tid, 256, f);
    if (tid >= 192 && tid < 192 + SHD) sad[tid - 192] = ldw(ad_, tid - 192, f);
    __syncthreads();
    int n = blockIdx.x * 256 + tid;
    if (n >= NN) return;
    float xr[FIN];
    if (f) {
        const float* xp = (const float*)x + (size_t)n * FIN;
        for (int k = 0; k < FIN; k++) xr[k] = xp[k];
    } else {
        const bf16* xp = (const bf16*)x + (size_t)n * FIN;
        for (int k = 0; k < FIN; k++) xr[k] = b2f(xp[k]);
    }
    float o[SHD];
    for (int j = 0; j < SHD; j++) o[j] = 0.f;
    for (int k = 0; k < FIN; k++) {
        float xv = xr[k];
        for (int j = 0; j < SHD; j++) o[j] += xv * sW[k * SHD + j];
    }
    ushort4* row = (ushort4*)(hWb + (size_t)n * SHD);
    for (int q = 0; q < 8; q++) {
        ushort4 v; v.x = f2b(o[q*4]); v.y = f2b(o[q*4+1]); v.z = f2b(o[q*4+2]); v.w = f2b(o[q*4+3]);
        row[q] = v;
    }
    for (int h = 0; h < NH; h++) {
        float e2 = 0.f;
        for (int c = 0; c < 4; c++) e2 += o[h * 4 + c] * sad[h * 4 + c];
        ed[(size_t)n * NH + h] = e2;
    }
}

// ---------------- GAT transform (layers 2/3: list-driven, DIN=32) -----------
__global__ void k_transform1(const int* __restrict__ list, const int* __restrict__ cntp,
                             int cap,
                             const float* x, const void* W, const void* ad_,
                             const int* flag, unsigned short* hWb, float* ed) {
    __shared__ float sW[SHD * SHD];
    __shared__ float sad[SHD];
    int tid = threadIdx.x;
    int f = flag[0];
    cp(sW, W, SHD * SHD, tid, 256, f);
    if (tid >= 192 && tid < 192 + SHD) sad[tid - 192] = ldw(ad_, tid - 192, f);
    __syncthreads();
    int cnt = cntp[0]; if (cnt > cap) cnt = cap;
    int ii = blockIdx.x * 256 + tid;
    if (ii >= cnt) return;
    int n = list[ii];
    float xr[SHD];
    const float4* xp4 = (const float4*)(x + (size_t)n * SHD);
#pragma unroll
    for (int q = 0; q < 8; q++) {
        float4 v = xp4[q];
        xr[q*4] = v.x; xr[q*4+1] = v.y; xr[q*4+2] = v.z; xr[q*4+3] = v.w;
    }
    float o[SHD];
    for (int j = 0; j < SHD; j++) o[j] = 0.f;
    for (int k = 0; k < SHD; k++) {
        float xv = xr[k];
        for (int j = 0; j < SHD; j++) o[j] += xv * sW[k * SHD + j];
    }
    ushort4* row = (ushort4*)(hWb + (size_t)n * SHD);
    for (int q = 0; q < 8; q++) {
        ushort4 v; v.x = f2b(o[q*4]); v.y = f2b(o[q*4+1]); v.z = f2b(o[q*4+2]); v.w = f2b(o[q*4+3]);
        row[q] = v;
    }
    for (int h = 0; h < NH; h++) {
        float e2 = 0.f;
        for (int c = 0; c < 4; c++) e2 += o[h * 4 + c] * sad[h * 4 + c];
        ed[(size_t)n * NH + h] = e2;
    }
}

// ------- GAT aggregation: list-driven, 2 entries/wave, 6-deep pipeline ------
// Round-8-proven inner loop (45.5us at full N); now only runs over frontier
// lists (<=4096 entries) so each instance is a few microseconds.
__global__ void k_aggregate(const int* __restrict__ list, const int* __restrict__ cntp,
                            int cap,
                            const int* __restrict__ rstart, const int* __restrict__ rdeg,
                            const int* __restrict__ csr,
                            const unsigned short* __restrict__ hWb,
                            const float* __restrict__ ed,
                            const float* __restrict__ prm,
                            float* __restrict__ out) {
    int gid = blockIdx.x * 256 + threadIdx.x;
    int lane = threadIdx.x & 63;
    int cnt = cntp[0]; if (cnt > cap) cnt = cap;
    int idx = (gid >> 6) * 2 + (lane >> 5);
    if (idx >= cnt) return;
    int n = list[idx];
    int l32 = lane & 31;
    int h = l32 & 7, k = l32 >> 3;
    float4 asv = *(const float4*)(prm + h * 4);
    float ednh = ed[(size_t)n * NH + h];
    int base = rstart[n];
    int deg = rdeg[n];
    float den = 0.f;
    f32x2 acc01 = {0.f, 0.f}, acc23 = {0.f, 0.f};
    int t = k;
    int s0 = -1, s1 = -1, s2 = -1, s3 = -1, s4 = -1, s5 = -1;
    if (t <= deg)      s0 = (t == 0) ? n : __builtin_nontemporal_load(csr + base + t - 1);
    if (t + 4 <= deg)  s1 = __builtin_nontemporal_load(csr + base + t + 3);
    if (t + 8 <= deg)  s2 = __builtin_nontemporal_load(csr + base + t + 7);
    if (t + 12 <= deg) s3 = __builtin_nontemporal_load(csr + base + t + 11);
    if (t + 16 <= deg) s4 = __builtin_nontemporal_load(csr + base + t + 15);
    if (t + 20 <= deg) s5 = __builtin_nontemporal_load(csr + base + t + 19);
    while (s0 >= 0) {
        uint2 hv0 = *(const uint2*)(hWb + (size_t)s0 * SHD + h * 4);
        bool b1 = (s1 >= 0), b2 = (s2 >= 0), b3 = (s3 >= 0), b4 = (s4 >= 0), b5 = (s5 >= 0);
        uint2 hv1, hv2, hv3, hv4, hv5;
        if (b1) hv1 = *(const uint2*)(hWb + (size_t)s1 * SHD + h * 4);
        if (b2) hv2 = *(const uint2*)(hWb + (size_t)s2 * SHD + h * 4);
        if (b3) hv3 = *(const uint2*)(hWb + (size_t)s3 * SHD + h * 4);
        if (b4) hv4 = *(const uint2*)(hWb + (size_t)s4 * SHD + h * 4);
        if (b5) hv5 = *(const uint2*)(hWb + (size_t)s5 * SHD + h * 4);
        int tn = t + 24;
        int p0 = -1, p1 = -1, p2 = -1, p3 = -1, p4 = -1, p5 = -1;
        if (tn <= deg)      p0 = __builtin_nontemporal_load(csr + base + tn - 1);
        if (tn + 4 <= deg)  p1 = __builtin_nontemporal_load(csr + base + tn + 3);
        if (tn + 8 <= deg)  p2 = __builtin_nontemporal_load(csr + base + tn + 7);
        if (tn + 12 <= deg) p3 = __builtin_nontemporal_load(csr + base + tn + 11);
        if (tn + 16 <= deg) p4 = __builtin_nontemporal_load(csr + base + tn + 15);
        if (tn + 20 <= deg) p5 = __builtin_nontemporal_load(csr + base + tn + 19);
        {
            f32x2 h01, h23;
            h01.x = __uint_as_float(hv0.x << 16);
            h01.y = __uint_as_float(hv0.x & 0xffff0000u);
            h23.x = __uint_as_float(hv0.y << 16);
            h23.y = __uint_as_float(hv0.y & 0xffff0000u);
            f32x2 d2 = h01 * (f32x2){asv.x, asv.y} + h23 * (f32x2){asv.z, asv.w};
            float e = d2.x + d2.y + ednh;
            e = fmaxf(e, 0.2f * e);
            float a = __expf(e);
            den += a;
            f32x2 av = {a, a};
            acc01 += av * h01;
            acc23 += av * h23;
        }
        if (b1) {
            f32x2 h01, h23;
            h01.x = __uint_as_float(hv1.x << 16);
            h01.y = __uint_as_float(hv1.x & 0xffff0000u);
            h23.x = __uint_as_float(hv1.y << 16);
            h23.y = __uint_as_float(hv1.y & 0xffff0000u);
            f32x2 d2 = h01 * (f32x2){asv.x, asv.y} + h23 * (f32x2){asv.z, asv.w};
            float e = d2.x + d2.y + ednh;
            e = fmaxf(e, 0.2f * e);
            float a = __expf(e);
            den += a;
            f32x2 av = {a, a};
            acc01 += av * h01;
            acc23 += av * h23;
        }
        if (b2) {
            f32x2 h01, h23;
            h01.x = __uint_as_float(hv2.x << 16);
            h01.y = __uint_as_float(hv2.x & 0xffff0000u);
            h23.x = __uint_as_float(hv2.y << 16);
            h23.y = __uint_as_float(hv2.y & 0xffff0000u);
            f32x2 d2 = h01 * (f32x2){asv.x, asv.y} + h23 * (f32x2){asv.z, asv.w};
            float e = d2.x + d2.y + ednh;
            e = fmaxf(e, 0.2f * e);
            float a = __expf(e);
            den += a;
            f32x2 av = {a, a};
            acc01 += av * h01;
            acc23 += av * h23;
        }
        if (b3) {
            f32x2 h01, h23;
            h01.x = __uint_as_float(hv3.x << 16);
            h01.y = __uint_as_float(hv3.x & 0xffff0000u);
            h23.x = __uint_as_float(hv3.y << 16);
            h23.y = __uint_as_float(hv3.y & 0xffff0000u);
            f32x2 d2 = h01 * (f32x2){asv.x, asv.y} + h23 * (f32x2){asv.z, asv.w};
            float e = d2.x + d2.y + ednh;
            e = fmaxf(e, 0.2f * e);
            float a = __expf(e);
            den += a;
            f32x2 av = {a, a};
            acc01 += av * h01;
            acc23 += av * h23;
        }
        if (b4) {
            f32x2 h01, h23;
            h01.x = __uint_as_float(hv4.x << 16);
            h01.y = __uint_as_float(hv4.x & 0xffff0000u);
            h23.x = __uint_as_float(hv4.y << 16);
            h23.y = __uint_as_float(hv4.y & 0xffff0000u);
            f32x2 d2 = h01 * (f32x2){asv.x, asv.y} + h23 * (f32x2){asv.z, asv.w};
            float e = d2.x + d2.y + ednh;
            e = fmaxf(e, 0.2f * e);
            float a = __expf(e);
            den += a;
            f32x2 av = {a, a};
            acc01 += av * h01;
            acc23 += av * h23;
        }
        if (b5) {
            f32x2 h01, h23;
            h01.x = __uint_as_float(hv5.x << 16);
            h01.y = __uint_as_float(hv5.x & 0xffff0000u);
            h23.x = __uint_as_float(hv5.y << 16);
            h23.y = __uint_as_float(hv5.y & 0xffff0000u);
            f32x2 d2 = h01 * (f32x2){asv.x, asv.y} + h23 * (f32x2){asv.z, asv.w};
            float e = d2.x + d2.y + ednh;
            e = fmaxf(e, 0.2f * e);
            float a = __expf(e);
            den += a;
            f32x2 av = {a, a};
            acc01 += av * h01;
            acc23 += av * h23;
        }
        s0 = p0; s1 = p1; s2 = p2; s3 = p3; s4 = p4; s5 = p5; t = tn;
    }
    for (int off = 16; off >= 8; off >>= 1) {
        den      += __shfl_down(den, off, 32);
        acc01.x  += __shfl_down(acc01.x, off, 32);
        acc01.y  += __shfl_down(acc01.y, off, 32);
        acc23.x  += __shfl_down(acc23.x, off, 32);
        acc23.y  += __shfl_down(acc23.y, off, 32);
    }
    if (k == 0) {
        float inv = 1.f / (den + 1e-16f);
        float4 bv = *(const float4*)(prm + 32 + h * 4);
        float v0 = acc01.x * inv + bv.x;
        float v1 = acc01.y * inv + bv.y;
        float v2 = acc23.x * inv + bv.z;
        float v3 = acc23.y * inv + bv.w;
        v0 = (v0 > 0.f) ? v0 : expm1f(v0);
        v1 = (v1 > 0.f) ? v1 : expm1f(v1);
        v2 = (v2 > 0.f) ? v2 : expm1f(v2);
        v3 = (v3 > 0.f) ? v3 : expm1f(v3);
        *(float4*)(out + (size_t)n * SHD + h * 4) = make_float4(v0, v1, v2, v3);
    }
}

// ---------------- Temporal tail ---------------------------------------------
// Round-5-verified design. LSTM weights pinned in registers via asm("+v")
// (defeats remat); L2 warm sweep + MLP matvecs use 8-wide batched loads.
template<typename T>
__device__ __forceinline__ void lstm_load_regs(
        const T* Wih0, const T* Whh0, const T* bih0, const T* bhh0,
        const T* Wih1, const T* Whh1, const T* bih1, const T* bhh1,
        const T* xin, int l, bool bl, float* xs,
        float& wa, float& ba, float& wb, float& bb, float& ba2, float& bb2,
        float* Wa, float* Wb, float* Ua, float* Va, float* Ub, float* Vb) {
#pragma unroll
    for (int t = 0; t < SEQL; t++) xs[t] = cvf(xin[t]);
    wa = cvf(Wih0[l]);
    ba = cvf(bih0[l]) + cvf(bhh0[l]);
    wb = bl ? cvf(Wih0[64 + l]) : 0.f;
    bb = bl ? (cvf(bih0[64 + l]) + cvf(bhh0[64 + l])) : 0.f;
    ba2 = cvf(bih1[l]) + cvf(bhh1[l]);
    bb2 = bl ? (cvf(bih1[64 + l]) + cvf(bhh1[64 + l])) : 0.f;
#pragma unroll
    for (int j = 0; j < 21; j++) {
        Wa[j] = cvf(Whh0[l * 21 + j]);
        Wb[j] = bl ? cvf(Whh0[(64 + l) * 21 + j]) : 0.f;
        Ua[j] = cvf(Wih1[l * 21 + j]);
        Va[j] = cvf(Whh1[l * 21 + j]);
        Ub[j] = bl ? cvf(Wih1[(64 + l) * 21 + j]) : 0.f;
        Vb[j] = bl ? cvf(Whh1[(64 + l) * 21 + j]) : 0.f;
    }
}

__device__ __forceinline__ void warm_sweep(const void* p, int nbytes, int t2) {
    const uint4* s = (const uint4*)p;
    int nv = nbytes >> 4;
    unsigned acc = 0;
    for (int i = t2; i < nv; i += 1024) {
        uint4 v0 = s[i];
        uint4 v1 = (i + 128 < nv) ? s[i + 128] : make_uint4(0,0,0,0);
        uint4 v2 = (i + 256 < nv) ? s[i + 256] : make_uint4(0,0,0,0);
        uint4 v3 = (i + 384 < nv) ? s[i + 384] : make_uint4(0,0,0,0);
        uint4 v4 = (i + 512 < nv) ? s[i + 512] : make_uint4(0,0,0,0);
        uint4 v5 = (i + 640 < nv) ? s[i + 640] : make_uint4(0,0,0,0);
        uint4 v6 = (i + 768 < nv) ? s[i + 768] : make_uint4(0,0,0,0);
        uint4 v7 = (i + 896 < nv) ? s[i + 896] : make_uint4(0,0,0,0);
        acc ^= v0.x ^ v1.x ^ v2.x ^ v3.x ^ v4.x ^ v5.x ^ v6.x ^ v7.x;
    }
    asm volatile("" :: "v"(acc));
}

template<typename T>
__device__ __forceinline__ float matvec_t(const T* W, const float* vin,
                                          float bias, int n, int col, int ncol) {
    float acc = bias;
    int k2 = 0;
    for (; k2 + 8 <= n; k2 += 8) {
        float w0 = cvf(W[(k2 + 0) * ncol + col]);
        float w1 = cvf(W[(k2 + 1) * ncol + col]);
        float w2 = cvf(W[(k2 + 2) * ncol + col]);
        float w3 = cvf(W[(k2 + 3) * ncol + col]);
        float w4 = cvf(W[(k2 + 4) * ncol + col]);
        float w5 = cvf(W[(k2 + 5) * ncol + col]);
        float w6 = cvf(W[(k2 + 6) * ncol + col]);
        float w7 = cvf(W[(k2 + 7) * ncol + col]);
        acc += vin[k2 + 0] * w0; acc += vin[k2 + 1] * w1;
        acc += vin[k2 + 2] * w2; acc += vin[k2 + 3] * w3;
        acc += vin[k2 + 4] * w4; acc += vin[k2 + 5] * w5;
        acc += vin[k2 + 6] * w6; acc += vin[k2 + 7] * w7;
    }
    for (; k2 < n; k2++) acc += vin[k2] * cvf(W[k2 * ncol + col]);
    return acc;
}
__device__ __forceinline__ float matvec(const void* W, const float* vin,
                                        float bias, int n, int col, int ncol, int f) {
    return f ? matvec_t<float>((const float*)W, vin, bias, n, col, ncol)
             : matvec_t<bf16>((const bf16*)W, vin, bias, n, col, ncol);
}

__global__ __launch_bounds__(256, 1)
void k_tail(const void* trend, const void* seasonal, const void* residual,
                       const void* cv, const int* tgtp,
                       const void* tWih0, const void* tWhh0, const void* tbih0, const void* tbhh0,
                       const void* tWih1, const void* tWhh1, const void* tbih1, const void* tbhh1,
                       const void* sWih0, const void* sWhh0, const void* sbih0, const void* sbhh0,
                       const void* sWih1, const void* sWhh1, const void* sbih1, const void* sbhh1,
                       const void* res_W, const void* res_b,
                       const void* pg_W, const void* pg_b,
                       const void* f1_W, const void* f1_b,
                       const void* ln_g, const void* ln_b,
                       const void* f2_W, const void* f2_b,
                       const void* f3_W, const void* f3_b,
                       const int* flag, const float* A, void* out) {
    __shared__ __align__(16) float SH1[2][24];
    __shared__ __align__(16) float SH2[2][24];
    __shared__ float comb[97];
    __shared__ float gf[96];
    __shared__ float h1v[64];
    __shared__ float h2s[32];
    __shared__ float sbias[336];  // pg_b@0 f1_b@96 f2_b@160 f3_b@192 ln_g@208 ln_b@272
    __shared__ float stats[2];
    const int tid = threadIdx.x;
    const int f = flag[0];
    const int w = tid >> 6, l = tid & 63;

    if (tid < 96) {
        if (tid < 48) SH1[tid / 24][tid % 24] = 0.f;
        else { int u = tid - 48; SH2[u / 24][u % 24] = 0.f; }
    }
    __syncthreads();

    if (w < 2) {
        const void* Wih0 = w ? sWih0 : tWih0;
        const void* Whh0 = w ? sWhh0 : tWhh0;
        const void* bih0 = w ? sbih0 : tbih0;
        const void* bhh0 = w ? sbhh0 : tbhh0;
        const void* Wih1 = w ? sWih1 : tWih1;
        const void* Whh1 = w ? sWhh1 : tWhh1;
        const void* bih1 = w ? sbih1 : tbih1;
        const void* bhh1 = w ? sbhh1 : tbhh1;
        const void* xin  = w ? seasonal : trend;
        const bool bl = (l < 20);
        float xs[SEQL];
        float wa, ba, wb, bb, ba2, bb2;
        float Wa[21], Wb[21], Ua[21], Va[21], Ub[21], Vb[21];
        if (f) {
            lstm_load_regs<float>((const float*)Wih0, (const float*)Whh0,
                (const float*)bih0, (const float*)bhh0,
                (const float*)Wih1, (const float*)Whh1,
                (const float*)bih1, (const float*)bhh1,
                (const float*)xin, l, bl, xs, wa, ba, wb, bb, ba2, bb2,
                Wa, Wb, Ua, Va, Ub, Vb);
        } else {
            lstm_load_regs<bf16>((const bf16*)Wih0, (const bf16*)Whh0,
                (const bf16*)bih0, (const bf16*)bhh0,
                (const bf16*)Wih1, (const bf16*)Whh1,
                (const bf16*)bih1, (const bf16*)bhh1,
                (const bf16*)xin, l, bl, xs, wa, ba, wb, bb, ba2, bb2,
                Wa, Wb, Ua, Va, Ub, Vb);
        }
#pragma unroll
        for (int j = 0; j < 21; j++) {
            asm volatile("" : "+v"(Wa[j]), "+v"(Wb[j]));
            asm volatile("" : "+v"(Ua[j]), "+v"(Va[j]));
            asm volatile("" : "+v"(Ub[j]), "+v"(Vb[j]));
        }
#pragma unroll
        for (int t = 0; t < SEQL; t++) asm volatile("" : "+v"(xs[t]));
        asm volatile("" : "+v"(wa), "+v"(ba));
        asm volatile("" : "+v"(wb), "+v"(bb));
        asm volatile("" : "+v"(ba2), "+v"(bb2));

        float h1r = 0.f, c1 = 0.f, h2r = 0.f, c2 = 0.f;
#pragma unroll 1
        for (int t = 0; t < SEQL; t++) {
            float aa = ba + xs[t] * wa;
            float ab = bb + xs[t] * wb;
#pragma unroll
            for (int q = 0; q < 5; q++) {
                float4 v = *(const float4*)&SH1[w][q * 4];
                aa += v.x * Wa[q*4];   ab += v.x * Wb[q*4];
                aa += v.y * Wa[q*4+1]; ab += v.y * Wb[q*4+1];
                aa += v.z * Wa[q*4+2]; ab += v.z * Wb[q*4+2];
                aa += v.w * Wa[q*4+3]; ab += v.w * Wb[q*4+3];
            }
            { float v20 = SH1[w][20]; aa += v20 * Wa[20]; ab += v20 * Wb[20]; }
            float fj = __shfl(aa, 21 + l);
            float gj = __shfl(aa, 42 + l);
            float oa = __shfl(aa, 63);
            float ob = __shfl(ab, (l == 0) ? 0 : (l - 1));
            float oj = (l == 0) ? oa : ob;
            if (l < 21) {
                c1 = sigm(fj) * c1 + sigm(aa) * tanhf(gj);
                h1r = sigm(oj) * tanhf(c1);
                SH1[w][l] = h1r;
            }
            __threadfence_block();
            float a2 = ba2, b2v = bb2;
#pragma unroll
            for (int q = 0; q < 5; q++) {
                float4 u = *(const float4*)&SH1[w][q * 4];
                float4 v = *(const float4*)&SH2[w][q * 4];
                a2  += u.x * Ua[q*4]   + v.x * Va[q*4];
                b2v += u.x * Ub[q*4]   + v.x * Vb[q*4];
                a2  += u.y * Ua[q*4+1] + v.y * Va[q*4+1];
                b2v += u.y * Ub[q*4+1] + v.y * Vb[q*4+1];
                a2  += u.z * Ua[q*4+2] + v.z * Va[q*4+2];
                b2v += u.z * Ub[q*4+2] + v.z * Vb[q*4+2];
                a2  += u.w * Ua[q*4+3] + v.w * Va[q*4+3];
                b2v += u.w * Ub[q*4+3] + v.w * Vb[q*4+3];
            }
            { float u20 = SH1[w][20], v20 = SH2[w][20];
              a2  += u20 * Ua[20] + v20 * Va[20];
              b2v += u20 * Ub[20] + v20 * Vb[20]; }
            float fj2 = __shfl(a2, 21 + l);
            float gj2 = __shfl(a2, 42 + l);
            float oa2 = __shfl(a2, 63);
            float ob2 = __shfl(b2v, (l == 0) ? 0 : (l - 1));
            float oj2 = (l == 0) ? oa2 : ob2;
            if (l < 21) {
                c2 = sigm(fj2) * c2 + sigm(a2) * tanhf(gj2);
                h2r = sigm(oj2) * tanhf(c2);
                SH2[w][l] = h2r;
            }
            __threadfence_block();
        }
        if (l < 21) comb[(w == 0 ? 32 : 53) + l] = h2r;
    } else {
        int t2 = tid - 128;   // 0..127
        if (t2 < TRH)
            comb[74 + t2] = relu_nan(ldw(residual, SEQL - 1, f) * ldw(res_W, t2, f)
                                     + ldw(res_b, t2, f));
        if (t2 == TRH) comb[96] = ldw(cv, 0, f);
        if (t2 >= 32 && t2 < 64) {
            int tgt = tgtp[0];
            comb[t2 - 32] = A[(size_t)tgt * SHD + (t2 - 32)];
        }
        for (int i = t2; i < 336; i += 128) {
            float v;
            if (i < 96)       v = ldw(pg_b, i, f);
            else if (i < 160) v = ldw(f1_b, i - 96, f);
            else if (i < 192) v = ldw(f2_b, i - 160, f);
            else if (i < 206) v = ldw(f3_b, i - 192, f);
            else if (i < 208) v = 0.f;
            else if (i < 272) v = ldw(ln_g, i - 208, f);
            else              v = ldw(ln_b, i - 272, f);
            sbias[i] = v;
        }
        int esz = f ? 4 : 2;
        warm_sweep(pg_W, 9312 * esz, t2);
        warm_sweep(f1_W, 6144 * esz, t2);
        warm_sweep(f2_W, 2048 * esz, t2);
        warm_sweep(f3_W,  448 * esz, t2);
    }
    __syncthreads();

    if (tid < 96)
        gf[tid] = comb[tid] * sigm(matvec(pg_W, comb, sbias[tid], 97, tid, 96, f));
    __syncthreads();
    if (tid < 64)
        h1v[tid] = matvec(f1_W, gf, sbias[96 + tid], 96, tid, 64, f);
    __syncthreads();
    if (tid == 0) {
        float mu = 0.f;
        for (int j = 0; j < 64; j++) mu += h1v[j];
        mu /= 64.f;
        float var = 0.f;
        for (int j = 0; j < 64; j++) { float d = h1v[j] - mu; var += d * d; }
        var /= 64.f;
        stats[0] = mu; stats[1] = rsqrtf(var + 1e-5f);
    }
    __syncthreads();
    if (tid < 64)
        h1v[tid] = relu_nan((h1v[tid] - stats[0]) * stats[1] * sbias[208 + tid] + sbias[272 + tid]);
    __syncthreads();
    if (tid < 32)
        h2s[tid] = relu_nan(matvec(f2_W, h1v, sbias[160 + tid], 64, tid, 32, f));
    __syncthreads();
    if (tid < SEQL) {
        float acc = matvec(f3_W, h2s, sbias[192 + tid], 32, tid, 14, f);
        if (acc != acc) acc = 3333.0f;
        if (f) ((float*)out)[tid] = acc;
        else   ((bf16*)out)[tid] = __float2bfloat16(acc);
    }
}

// ---------------- host helpers ----------------
static inline unsigned short h_f2bf(float f) {
    union { float f; unsigned u; } x; x.f = f;
    return (unsigned short)(x.u >> 16);
}
static unsigned short g_diag[SEQL];

// ---------------- launch ----------------
extern "C" void kernel_launch(void* const* d_in, const int* in_sizes, int n_in,
                              void* d_out, int out_size, void* d_ws, size_t ws_size,
                              hipStream_t stream) {
    const int* ei  = (const int*)d_in[1];
    const int* tgt = (const int*)d_in[6];

    const size_t HWB  = sizeof(unsigned short) * (size_t)NN * SHD;
    const size_t EDB  = sizeof(float) * (size_t)NN * NH;
    const size_t AB   = sizeof(float) * (size_t)NN * SHD;
    const size_t CSRB = sizeof(int) * (size_t)NBUK * CAP;
    const size_t LSTB = sizeof(int) * (size_t)(EC1 + EC2 + 16);
    const size_t NEED = 256 + 1024 + sizeof(int) * (size_t)(NC + NBUK + 8 + 2 * NN + 32)
                      + LSTB + CSRB + 512 + HWB + EDB + AB;
    if (ws_size < NEED ||
        sizeof(int) * (size_t)NC * CAPG1 > CSRB ||
        sizeof(int) * (size_t)NBUK * CAP > HWB + EDB + AB) {
        for (int i = 0; i < SEQL; i++) g_diag[i] = h_f2bf(7777.0f);
        hipMemcpyAsync(d_out, g_diag, SEQL * sizeof(unsigned short),
                       hipMemcpyHostToDevice, stream);
        return;
    }

    char* p = (char*)d_ws;
    int*   flag = (int*)p;   p += 256;
    float* prm  = (float*)p; p += 1024;
    int* g1     = (int*)p; p += sizeof(int) * NC;
    int* g2     = (int*)p; p += sizeof(int) * NBUK;
    int* cnts   = (int*)p; p += sizeof(int) * 8;      // c1, c2, c3 (zeroed with g1/g2)
    int* rstart = (int*)p; p += sizeof(int) * NN;
    int* rdeg   = (int*)p; p += sizeof(int) * (NN + 32);
    int* l1     = (int*)p; p += sizeof(int) * EC1;
    int* l3     = (int*)p; p += sizeof(int) * 8;
    int* l2     = (int*)p; p += sizeof(int) * EC2;
    int* csr    = (int*)p; p += CSRB;
    p = (char*)(((uintptr_t)p + 255) & ~(uintptr_t)255);
    unsigned short* hWb = (unsigned short*)p; p += HWB;
    float* ed = (float*)p; p += EDB;
    float* A  = (float*)p; p += AB;
    int* rec1 = csr;
    int* rec2 = (int*)hWb;
    int* c1 = cnts; int* c2 = cnts + 1; int* c3 = cnts + 2;

    dim3 b256(256);
    dim3 gN((NN + 255) / 256);

    PatternAwareSTGAT_94489281309_kernel<<<dim3(1), dim3(64), 0, stream>>>(
        (const unsigned int*)d_in[0], flag,
        d_in[8], d_in[10], d_in[12], d_in[14], d_in[16], d_in[18], prm);

    hipMemsetAsync(g1, 0, sizeof(int) * (NC + NBUK + 8), stream);
    k_p1<<<dim3(NBC1), b256, 0, stream>>>(ei, g1, rec1);
    k_p2<<<dim3(NC * PB2), b256, 0, stream>>>(rec1, g1, g2, rec2);
    k_build<<<dim3(NBUK), b256, 0, stream>>>(rec2, g2, csr, rstart, rdeg);

    // frontier lists: F1 (layer-2 agg / layer-3 transform), F2 (layer-1 agg /
    // layer-2 transform), l3 = {tgt} (layer-3 agg)
    k_front<<<dim3(1), dim3(64), 0, stream>>>(rstart, rdeg, csr, tgt, l1, c1, l3, c3);
    k_front2<<<dim3(EC1), dim3(64), 0, stream>>>(rstart, rdeg, csr, l1, c1, l2, c2);

    k_transform0<<<gN, b256, 0, stream>>>(d_in[0], d_in[7], d_in[9], flag, hWb, ed);
    k_aggregate<<<dim3(EC2 * 32 / 256), b256, 0, stream>>>(l2, c2, EC2,
        rstart, rdeg, csr, hWb, ed, prm, A);
    k_transform1<<<dim3(EC2 / 256), b256, 0, stream>>>(l2, c2, EC2,
        A, d_in[11], d_in[13], flag, hWb, ed);
    k_aggregate<<<dim3(EC1 * 32 / 256), b256, 0, stream>>>(l1, c1, EC1,
        rstart, rdeg, csr, hWb, ed, prm + 64, A);
    k_transform1<<<dim3(1), b256, 0, stream>>>(l1, c1, EC1,
        A, d_in[15], d_in[17], flag, hWb, ed);
    k_aggregate<<<dim3(1), b256, 0, stream>>>(l3, c3, 8,
        rstart, rdeg, csr, hWb, ed, prm + 128, A);

    k_tail<<<dim3(1), b256, 0, stream>>>(
        d_in[2], d_in[3], d_in[4], d_in[5], tgt,
        d_in[19], d_in[20], d_in[21], d_in[22],
        d_in[23], d_in[24], d_in[25], d_in[26],
        d_in[27], d_in[28], d_in[29], d_in[30],
        d_in[31], d_in[32], d_in[33], d_in[34],
        d_in[35], d_in[36],
        d_in[37], d_in[38],
        d_in[39], d_in[40],
        d_in[41], d_in[42],
        d_in[43], d_in[44],
        d_in[45], d_in[46],
        flag, A, d_out);
}